// Round 8
// baseline (735.550 us; speedup 1.0000x reference)
//
#include <hip/hip_runtime.h>
#include <cstdint>
#include <cstddef>

#define KNB 20
#define NPTS 8192
#define BATCH 2
#define TOTAL (BATCH * NPTS)
#define NCELL 4096               // 16^3 grid per batch
#define SENT 0x7F800000FFFFFFFFULL  // d2=+inf, low=~0 (u64-max real key bound)
#define CAP 1024                 // per-wave candidate buffer (ints)

typedef _Float16 f16x4 __attribute__((ext_vector_type(4)));
typedef float f32x4 __attribute__((ext_vector_type(4)));

// ---------------------------------------------------------------------------
// Grid build (per batch, 16^3 cells, counting sort). All tiny (~25 µs).
// ---------------------------------------------------------------------------
__global__ __launch_bounds__(256) void k_zero(int* __restrict__ cnt) {
  int g = blockIdx.x * 256 + threadIdx.x;
  if (g < 2 * BATCH * NCELL) cnt[g] = 0;   // cnt + cnt2, contiguous
}

__global__ __launch_bounds__(256) void k_hist(const float* __restrict__ pts,
                                              int* __restrict__ cnt) {
  int p = blockIdx.x * 256 + threadIdx.x;
  if (p >= TOTAL) return;
  int b = p >> 13;
  int cx = min(15, (int)(pts[p * 3 + 0] * 16.f));
  int cy = min(15, (int)(pts[p * 3 + 1] * 16.f));
  int cz = min(15, (int)(pts[p * 3 + 2] * 16.f));
  atomicAdd(&cnt[b * NCELL + (cz * 16 + cy) * 16 + cx], 1);
}

__global__ __launch_bounds__(256) void k_scan(const int* __restrict__ cnt,
                                              int* __restrict__ cellStart) {
  __shared__ int ls[256];
  int b = blockIdx.x, t = threadIdx.x;
  const int* c = cnt + b * NCELL;
  int* cs = cellStart + b * (NCELL + 1);
  int base = t * 16;
  int s = 0;
#pragma unroll
  for (int i = 0; i < 16; i++) s += c[base + i];
  ls[t] = s;
  __syncthreads();
  for (int off = 1; off < 256; off <<= 1) {
    int v = (t >= off) ? ls[t - off] : 0;
    __syncthreads();
    ls[t] += v;
    __syncthreads();
  }
  int run = ls[t] - s;                  // exclusive prefix
#pragma unroll
  for (int i = 0; i < 16; i++) { cs[base + i] = run; run += c[base + i]; }
  if (t == 255) cs[NCELL] = run;        // sentinel = NPTS
}

// k_scatter: packed (x,y,z,orig_local_idx) per sorted slot. Coordinates are
// bit-exact copies of pts, so all downstream arithmetic is unchanged.
__global__ __launch_bounds__(256) void k_scatter(
    const float* __restrict__ pts, int* __restrict__ cnt2,
    const int* __restrict__ cellStart, float4* __restrict__ spk) {
  int p = blockIdx.x * 256 + threadIdx.x;
  if (p >= TOTAL) return;
  int b = p >> 13, pl = p & (NPTS - 1);
  float x = pts[p * 3 + 0], y = pts[p * 3 + 1], z = pts[p * 3 + 2];
  int cx = min(15, (int)(x * 16.f));
  int cy = min(15, (int)(y * 16.f));
  int cz = min(15, (int)(z * 16.f));
  int cell = (cz * 16 + cy) * 16 + cx;
  int pos = cellStart[b * (NCELL + 1) + cell] + atomicAdd(&cnt2[b * NCELL + cell], 1);
  spk[(size_t)b * NPTS + pos] = make_float4(x, y, z, __int_as_float(pl));
}

// ---------------------------------------------------------------------------
// K1: pointwise conv 3->64 + relu — SORTED space.
// ---------------------------------------------------------------------------
__global__ __launch_bounds__(256) void k_conv(const float4* __restrict__ spk,
                                              const float* __restrict__ w,
                                              const float* __restrict__ b,
                                              float* __restrict__ x0) {
  int gid = blockIdx.x * 256 + threadIdx.x;
  if (gid >= TOTAL * 64) return;
  int p = gid >> 6, c = gid & 63;
  float4 pp = spk[p];
  float acc = b[c] + pp.x * w[c] + pp.y * w[64 + c] + pp.z * w[128 + c];
  x0[gid] = fmaxf(acc, 0.f);
}

// ---------------------------------------------------------------------------
// K2: GRID KNN (R1-proven cascade) — SORTED-space queries and outputs.
//  Key = [d2:32][origid:13][sortpos:13] -> exact lax.top_k order.
// ---------------------------------------------------------------------------
__global__ __launch_bounds__(256) void k_knn(
    const float4* __restrict__ spk, const int* __restrict__ cellStart,
    int* __restrict__ idxbuf) {
  __shared__ int s_cand[4][CAP];       // 16 KB
  int tid = threadIdx.x;
  int wv = tid >> 6, lane = tid & 63;
  int q = blockIdx.x * 4 + wv;         // SORTED index
  int bq = q >> 13;
  const float4* bp = spk + (size_t)bq * NPTS;
  const int* cs = cellStart + bq * (NCELL + 1);
  float4 qp = bp[q & (NPTS - 1)];
  float qx = qp.x, qy = qp.y, qz = qp.z;
  int cx = min(15, (int)(qx * 16.f));
  int cy = min(15, (int)(qy * 16.f));
  int cz = min(15, (int)(qz * 16.f));

  unsigned long long key[KNB];
  float tau19 = __uint_as_float(0x7F800000u);
  int pass_ok = 0;

#define INS(KK)                                                              \
  if ((KK) < key[KNB - 1]) {                                                 \
    _Pragma("unroll")                                                        \
    for (int j = KNB - 1; j >= 0; j--) {                                     \
      bool cj = (KK) < key[j];                                               \
      bool cjm1 = (j > 0) && ((KK) < key[j - 1]);                            \
      if (cj) key[j] = cjm1 ? key[j - 1] : (KK);                             \
    }                                                                        \
  }

#define PASS(RR, WW, NRR, BOUND)                                             \
  {                                                                          \
    _Pragma("unroll")                                                        \
    for (int j = 0; j < KNB; j++) key[j] = SENT;                             \
    int sv = 0, lenv = 0;                                                    \
    if (lane < (NRR)) {                                                      \
      int dz = lane / (WW) - (RR), dy = lane % (WW) - (RR);                  \
      int z = cz + dz, y = cy + dy;                                          \
      if ((unsigned)z < 16u && (unsigned)y < 16u) {                          \
        int x0 = cx - (RR); if (x0 < 0) x0 = 0;                              \
        int x1 = cx + (RR); if (x1 > 15) x1 = 15;                            \
        int rb = (z * 16 + y) * 16;                                          \
        sv = cs[rb + x0];                                                    \
        lenv = cs[rb + x1 + 1] - sv;                                         \
      }                                                                      \
    }                                                                        \
    int pre = lenv;                                                          \
    _Pragma("unroll")                                                        \
    for (int off = 1; off < 64; off <<= 1) {                                 \
      int o = __shfl_up(pre, off);                                           \
      if (lane >= off) pre += o;                                             \
    }                                                                        \
    int T = __shfl(pre, 63);                                                 \
    int excl = pre - lenv;                                                   \
    asm volatile("s_waitcnt lgkmcnt(0)" ::: "memory"); /* WAR vs prior pass */\
    for (int k2 = 0; k2 < lenv; k2++) {                                      \
      int wpos = excl + k2;                                                  \
      if (wpos < CAP) s_cand[wv][wpos] = sv + k2;                            \
    }                                                                        \
    asm volatile("s_waitcnt lgkmcnt(0)" ::: "memory"); /* RAW: writes done */\
    int Tc = T < CAP ? T : CAP;                                              \
    for (int t = lane; t < Tc; t += 64) {                                    \
      int ci = s_cand[wv][t];                                                \
      float4 pk = bp[ci];                                                    \
      float dxv = qx - pk.x, dyv = qy - pk.y, dzv = qz - pk.z;               \
      float d2 = __fadd_rn(__fadd_rn(__fmul_rn(dxv, dxv),                    \
                                     __fmul_rn(dyv, dyv)),                   \
                           __fmul_rn(dzv, dzv));                             \
      unsigned long long kk =                                                \
          ((unsigned long long)__float_as_uint(d2) << 32) |                  \
          ((unsigned)__float_as_uint(pk.w) << 13) | (unsigned)ci;            \
      INS(kk)                                                                \
    }                                                                        \
    float h = __uint_as_float((unsigned)(key[0] >> 32));                     \
    _Pragma("unroll")                                                        \
    for (int kk2 = 2; kk2 <= 64; kk2 <<= 1) {                                \
      _Pragma("unroll")                                                      \
      for (int j = kk2 >> 1; j > 0; j >>= 1) {                               \
        float o = __shfl_xor(h, j);                                          \
        bool up = ((lane & kk2) == 0);                                       \
        bool lower = ((lane & j) == 0);                                      \
        bool takeMin = (up == lower);                                        \
        bool lt = h < o;                                                     \
        h = (takeMin == lt) ? h : o;                                         \
      }                                                                      \
    }                                                                        \
    tau19 = __shfl(h, 19);                                                   \
    pass_ok = (T <= CAP) && (tau19 < (BOUND));                               \
  }

  float fx = fminf(qx, 1.f - qx), fy = fminf(qy, 1.f - qy),
        fz = fminf(qz, 1.f - qz);
  int nearf = (fx < 0.13f) + (fy < 0.13f) + (fz < 0.13f);

  if (nearf < 2) PASS(2, 5, 25, 0.0155f)
  if (!pass_ok)  PASS(3, 7, 49, 0.0351f)
#undef PASS

  if (!pass_ok) {
    // exact rescan of all 8192 with tau filter, from scratch.
#pragma unroll
    for (int j = 0; j < KNB; j++) key[j] = SENT;
    for (int g = 0; g < 32; g++) {
      int i0 = g * 256 + lane * 4;
#pragma unroll
      for (int c = 0; c < 4; c++) {
        float4 pk = bp[i0 + c];
        float dxv = qx - pk.x, dyv = qy - pk.y, dzv = qz - pk.z;
        float d2 = __fadd_rn(__fadd_rn(__fmul_rn(dxv, dxv),
                                       __fmul_rn(dyv, dyv)),
                             __fmul_rn(dzv, dzv));
        if (d2 <= tau19) {
          unsigned long long kk =
              ((unsigned long long)__float_as_uint(d2) << 32) |
              ((unsigned)__float_as_uint(pk.w) << 13) | (unsigned)(i0 + c);
          INS(kk)
        }
      }
    }
  }
#undef INS

  int bqoff = bq * NPTS;
  for (int step = 0; step < KNB; step++) {
    unsigned long long p = key[0];
    unsigned long long m = p;
#pragma unroll
    for (int off = 32; off >= 1; off >>= 1) {
      unsigned long long o = __shfl_xor(m, off);
      m = (o < m) ? o : m;
    }
    if (lane == 0) idxbuf[q * KNB + step] = bqoff + (int)(m & 0x1FFFULL);
    if (p == m) {
#pragma unroll
      for (int j = 0; j < KNB - 1; j++) key[j] = key[j + 1];
      key[KNB - 1] = SENT;
    }
  }
}

// ---------------------------------------------------------------------------
// K3c: per-layer fold: W2 = pw2@aw1_bot -> f16 FRAGMENT layout (A-operand).
// ---------------------------------------------------------------------------
__global__ __launch_bounds__(256) void k_w2(const float* __restrict__ pw2,
                                            const float* __restrict__ pb2,
                                            const float* __restrict__ aw1,
                                            _Float16* __restrict__ W2A,
                                            float* __restrict__ c0) {
  int h = blockIdx.x, c = threadIdx.x;
  float a = 0.f;
  if (h < 64) {
#pragma unroll 8
    for (int j = 0; j < 64; j++)
      a += pw2[h * 64 + j] * aw1[(size_t)(64 + j) * 256 + c];
    int mt = c >> 4, lo = c & 15;
    int ks = h >> 4, hi = (h >> 2) & 3, el = h & 3;
    W2A[(size_t)(((mt * 4 + ks) * 64) + hi * 16 + lo) * 4 + el] = (_Float16)a;
  } else {
#pragma unroll 8
    for (int j = 0; j < 64; j++)
      a += pb2[j] * aw1[(size_t)(64 + j) * 256 + c];
    c0[c] = a;
  }
}

// ---------------------------------------------------------------------------
// K3f: fold pre-GEMM weights -> f16 B-frags (R3-proven). cols: kh|qh|v.
// ---------------------------------------------------------------------------
__global__ __launch_bounds__(256) void k_fold(const float* __restrict__ qkvw,
                                              const float* __restrict__ aw1,
                                              _Float16* __restrict__ WFB) {
  int id = blockIdx.x * 256 + threadIdx.x;   // 144 blocks x 256 = 36864
  int h = id & 63, c = id >> 6;
  float a = 0.f;
  if (c < 256) {
#pragma unroll 8
    for (int j = 0; j < 64; j++)
      a += qkvw[h * 192 + 64 + j] * aw1[(size_t)j * 256 + c];
  } else if (c < 512) {
    int cc = c - 256;
#pragma unroll 8
    for (int j = 0; j < 64; j++)
      a += qkvw[h * 192 + j] * aw1[(size_t)j * 256 + cc];
  } else {
    a = qkvw[h * 192 + 128 + (c - 512)];
  }
  int nt = c >> 4, lo = c & 15, ks = h >> 4, hi = (h >> 2) & 3, e = h & 3;
  WFB[(size_t)(((nt * 4 + ks) * 64) + hi * 16 + lo) * 4 + e] = (_Float16)a;
}

// ---------------------------------------------------------------------------
// K3: k_pre2 — MFMA GEMM producing kh|qh|v (R3-proven, unchanged).
// ---------------------------------------------------------------------------
__global__ __launch_bounds__(256) void k_pre2(const float* __restrict__ x,
                                              const f16x4* __restrict__ WFB,
                                              const float* __restrict__ c0,
                                              const float* __restrict__ ab1,
                                              float* __restrict__ v,
                                              float* __restrict__ kh,
                                              float* __restrict__ qh) {
  int tid = threadIdx.x;
  int wv = tid >> 6, lane = tid & 63;
  int mt = blockIdx.x * 4 + wv;
  int m0 = mt * 16;
  int lo = lane & 15, hi = lane >> 4;

  f16x4 af[4];
#pragma unroll
  for (int ks = 0; ks < 4; ks++) {
    float4 xv = *(const float4*)&x[(size_t)(m0 + lo) * 64 + ks * 16 + hi * 4];
    f16x4 a;
    a[0] = (_Float16)xv.x; a[1] = (_Float16)xv.y;
    a[2] = (_Float16)xv.z; a[3] = (_Float16)xv.w;
    af[ks] = a;
  }

#pragma unroll 4
  for (int nt = 0; nt < 36; nt++) {
    f32x4 acc = {0.f, 0.f, 0.f, 0.f};
#pragma unroll
    for (int ks = 0; ks < 4; ks++)
      acc = __builtin_amdgcn_mfma_f32_16x16x16f16(af[ks],
                                                  WFB[(nt * 4 + ks) * 64 + lane],
                                                  acc, 0, 0, 0);
    if (nt < 16) {
      int col = nt * 16 + lo;
#pragma unroll
      for (int r = 0; r < 4; r++)
        kh[(size_t)(m0 + hi * 4 + r) * 256 + col] = acc[r];
    } else if (nt < 32) {
      int col = (nt - 16) * 16 + lo;
      float bv = c0[col] + ab1[col];
#pragma unroll
      for (int r = 0; r < 4; r++)
        qh[(size_t)(m0 + hi * 4 + r) * 256 + col] = acc[r] + bv;
    } else {
      int col = (nt - 32) * 16 + lo;
#pragma unroll
      for (int r = 0; r < 4; r++)
        v[(size_t)(m0 + hi * 4 + r) * 64 + col] = acc[r];
    }
  }
}

// ---------------------------------------------------------------------------
// K4: attention — 2 queries/wave, SEQUENTIAL per-query pipeline (R8).
//  R7 post-mortem: VGPR=64 sits ON the occupancy cliff (waves halve at
//  vgpr=64) -> stuck at 4 waves/SIMD. Serializing the two queries' MFMA
//  blocks halves the B-frag live set (16 regs not 32) and scopes all
//  per-query state inside the loop; target <=56 VGPR -> 8 waves/SIMD.
//  launch_bounds(256,6) caps allocator inflation at ~85 (no spill band:
//  demand ~55 << 85; R5 lesson — never force below demand).
// ---------------------------------------------------------------------------
__global__ __launch_bounds__(256, 6) void k_attn(
    const float4* __restrict__ spk4, const float* __restrict__ v,
    const int* __restrict__ idxbuf, const float* __restrict__ kh,
    const float* __restrict__ qh,
    const float* __restrict__ pw1, const float* __restrict__ pb1,
    const float* __restrict__ pw2, const float* __restrict__ pb2,
    const _Float16* __restrict__ W2A,
    const float* __restrict__ aw2, const float* __restrict__ ab2,
    float* __restrict__ xout) {
  __shared__ __align__(16) _Float16 s_t1h[4][1280];  // 10 KB: 20 rows x 64
  __shared__ float s_sim[4][2][KNB];
  __shared__ int   s_nb[4][2][24];

  int tid = threadIdx.x;
  int wv = tid >> 6, lane = tid & 63;
  int q0 = blockIdx.x * 8 + wv * 2;          // this wave: queries q0, q0+1
  int lo = lane & 15, hi = lane >> 4;

  if (lane < KNB) {
    s_nb[wv][0][lane] = idxbuf[q0 * KNB + lane];
    s_nb[wv][1][lane] = idxbuf[(q0 + 1) * KNB + lane];
  }
  asm volatile("s_waitcnt lgkmcnt(0)" ::: "memory");  // s_nb visible to wave

  const f16x4* W2A4 = (const f16x4*)W2A;

#define RL(x, l) __uint_as_float(__builtin_amdgcn_readlane(__float_as_uint(x), (l)))
  for (int qq = 0; qq < 2; qq++) {           // runtime loop: small code, low VGPR
    float4 qp = spk4[q0 + qq];
    float px = qp.x, py = qp.y, pz = qp.z;
    float w1x = pw1[lane], w1y = pw1[64 + lane], w1z = pw1[128 + lane];
    float b1h = pb1[lane];

    // A: stage t1 (f16, swizzled, 20 rows) into the wave-private buffer.
#pragma unroll
    for (int n = 0; n < KNB; n++) {
      int g = s_nb[wv][qq][n];
      float4 np = spk4[g];
      float t1n = fmaxf(b1h + (px - np.x) * w1x + (py - np.y) * w1y +
                            (pz - np.z) * w1z, 0.f);
      s_t1h[wv][(n * 64 + lane) ^ ((n & 7) << 3)] = (_Float16)t1n;
    }
    asm volatile("s_waitcnt lgkmcnt(0)" ::: "memory");  // writes visible

    // B-frags: lane l -> B[k=ks*16+4*hi+e][nb=nt*16+lo]; cols>=20 = 0.
    f16x4 bf0[4], bf1[4];
#pragma unroll
    for (int ks = 0; ks < 4; ks++) {
      int i0 = ((lo * 64) + ks * 16 + hi * 4) ^ ((lane & 7) << 3);
      bf0[ks] = *(const f16x4*)&s_t1h[wv][i0];
      if (lo < 4) {
        int i1 = (((16 + lo) * 64) + ks * 16 + hi * 4) ^ ((lane & 7) << 3);
        bf1[ks] = *(const f16x4*)&s_t1h[wv][i1];
      } else {
        f16x4 z = {(_Float16)0.f, (_Float16)0.f, (_Float16)0.f, (_Float16)0.f};
        bf1[ks] = z;
      }
    }
    asm volatile("s_waitcnt lgkmcnt(0)" ::: "memory");  // frags in regs (WAR-safe)

    int g0 = s_nb[wv][qq][lo];
    int g1 = s_nb[wv][qq][(lo < 4) ? (16 + lo) : 0];  // lo>=4: dummy (isolated)
    const float* khr0 = &kh[(size_t)g0 * 256];
    const float* khr1 = &kh[(size_t)g1 * 256];
    const float* qhr  = &qh[(size_t)(q0 + qq) * 256];
    float sim0 = 0.f, sim1 = 0.f;

#pragma unroll 2
    for (int mt = 0; mt < 16; mt++) {
      f32x4 a0 = {0.f, 0.f, 0.f, 0.f}, a1 = {0.f, 0.f, 0.f, 0.f};
#pragma unroll
      for (int ks = 0; ks < 4; ks++) {
        f16x4 af = W2A4[(mt * 4 + ks) * 64 + lane];
        a0 = __builtin_amdgcn_mfma_f32_16x16x16f16(af, bf0[ks], a0, 0, 0, 0);
        a1 = __builtin_amdgcn_mfma_f32_16x16x16f16(af, bf1[ks], a1, 0, 0, 0);
      }
      int cb = mt * 16 + hi * 4;
      float4 w24 = *(const float4*)&aw2[cb];
      float4 kh0 = *(const float4*)&khr0[cb];
      float4 kh1 = *(const float4*)&khr1[cb];
      float4 qh4 = *(const float4*)&qhr[cb];
      sim0 += fmaxf(a0[0] + qh4.x - kh0.x, 0.f) * w24.x +
              fmaxf(a0[1] + qh4.y - kh0.y, 0.f) * w24.y +
              fmaxf(a0[2] + qh4.z - kh0.z, 0.f) * w24.z +
              fmaxf(a0[3] + qh4.w - kh0.w, 0.f) * w24.w;
      sim1 += fmaxf(a1[0] + qh4.x - kh1.x, 0.f) * w24.x +
              fmaxf(a1[1] + qh4.y - kh1.y, 0.f) * w24.y +
              fmaxf(a1[2] + qh4.z - kh1.z, 0.f) * w24.z +
              fmaxf(a1[3] + qh4.w - kh1.w, 0.f) * w24.w;
    }
    // reduce over hi (XOR 16/32 keeps lo fixed; lo>=4 garbage isolated).
    sim0 += __shfl_xor(sim0, 16); sim0 += __shfl_xor(sim0, 32);
    sim1 += __shfl_xor(sim1, 16); sim1 += __shfl_xor(sim1, 32);
    float ab2v = ab2[0];
    if (lane < 16) s_sim[wv][qq][lane] = sim0 + ab2v;
    if (lane < 4)  s_sim[wv][qq][16 + lane] = sim1 + ab2v;
    asm volatile("s_waitcnt lgkmcnt(0)" ::: "memory");  // s_sim visible

    // C: softmax; out = sum an*v[g] + (sum an*t1_n)@pw2 + pb2.
    // t1_n recomputed bit-identically (same inputs/ops as phase A).
    float mx = -3.402823466e38f;
#pragma unroll
    for (int n = 0; n < KNB; n++) mx = fmaxf(mx, s_sim[wv][qq][n]);
    float sum = 0.f;
#pragma unroll
    for (int n = 0; n < KNB; n++) sum += expf(s_sim[wv][qq][n] - mx);
    float inv = 1.f / sum;
    float o = 0.f;
    float sac = 0.f;
#pragma unroll
    for (int n = 0; n < KNB; n++) {
      float an = expf(s_sim[wv][qq][n] - mx) * inv;
      int g = s_nb[wv][qq][n];
      o += an * v[(size_t)g * 64 + lane];
      float4 np = spk4[g];
      float t1n = fmaxf(b1h + (px - np.x) * w1x + (py - np.y) * w1y +
                            (pz - np.z) * w1z, 0.f);
      sac += an * t1n;
    }
    float r = pb2[lane];
#pragma unroll 8
    for (int j = 0; j < 64; j++) r += RL(sac, j) * pw2[j * 64 + lane];
    xout[(size_t)(q0 + qq) * 64 + lane] = o + r;
  }
#undef RL
}

// ---------------------------------------------------------------------------
// K5a/K5b: parallel max-pool + head (order-invariant; sorted act OK).
// ---------------------------------------------------------------------------
__global__ __launch_bounds__(256) void k_pool(const float* __restrict__ x,
                                              float* __restrict__ pmax) {
  __shared__ float red[4][64];
  int b = blockIdx.x >> 6, blk = blockIdx.x & 63;
  int tid = threadIdx.x;
  int c = tid & 63, pg = tid >> 6;
  int p0 = blk * 128;
  float mx = -3.402823466e38f;
  for (int p = pg; p < 128; p += 4)
    mx = fmaxf(mx, x[((size_t)b * NPTS + p0 + p) * 64 + c]);
  red[pg][c] = mx;
  __syncthreads();
  if (tid < 64)
    pmax[(size_t)blockIdx.x * 64 + c] =
        fmaxf(fmaxf(red[0][c], red[1][c]), fmaxf(red[2][c], red[3][c]));
}

__global__ __launch_bounds__(256) void k_final2(const float* __restrict__ pmax,
                                                const float* __restrict__ fc1w,
                                                const float* __restrict__ fc1b,
                                                const float* __restrict__ fc3w,
                                                const float* __restrict__ fc3b,
                                                float* __restrict__ out) {
  __shared__ float red[4][64];
  __shared__ float m[64];
  __shared__ float h1[32];
  int b = blockIdx.x;
  int tid = threadIdx.x;
  int c = tid & 63, pg = tid >> 6;
  float mx = -3.402823466e38f;
  for (int blk = pg; blk < 64; blk += 4)
    mx = fmaxf(mx, pmax[(size_t)(b * 64 + blk) * 64 + c]);
  red[pg][c] = mx;
  __syncthreads();
  if (tid < 64)
    m[c] = fmaxf(fmaxf(red[0][c], red[1][c]), fmaxf(red[2][c], red[3][c]));
  __syncthreads();
  if (tid < 32) {
    float a = fc1b[tid];
#pragma unroll 8
    for (int k = 0; k < 64; k++) a += m[k] * fc1w[k * 32 + tid];
    h1[tid] = fmaxf(a, 0.f);
  }
  __syncthreads();
  if (tid < 3) {
    float a = fc3b[tid];
#pragma unroll
    for (int k = 0; k < 32; k++) a += h1[k] * fc3w[k * 3 + tid];
    out[b * 3 + tid] = a;
  }
}

// ---------------------------------------------------------------------------
// Workspace (peak ~44.8 MB):
//   idx @ 0 (1.31MB) | spk @ 1408KB (256KB; LIVE through both layers)
//   W2A @ 1664KB (32KB f16 frags) | c0 @ 1728KB (1KB) | pmax @ 1732KB (32KB)
//   cellStart @ 1764KB (33KB) | cnt+cnt2 @ 1800KB (64KB)
//   WFB @ 1864KB (73.7KB f16 frags)
//   v @ 2MB (4.2MB) | kh @ 6.5MB (16.8MB) | qh @ 23.5MB (16.8MB)
//   act @ 40.5MB (4.2MB)
// ---------------------------------------------------------------------------
extern "C" void kernel_launch(void* const* d_in, const int* in_sizes, int n_in,
                              void* d_out, int out_size, void* d_ws,
                              size_t ws_size, hipStream_t stream) {
  const float* pts    = (const float*)d_in[0];
  const float* conv_w = (const float*)d_in[1];
  const float* conv_b = (const float*)d_in[2];
  const float* fc1w = (const float*)d_in[21];
  const float* fc1b = (const float*)d_in[22];
  const float* fc3w = (const float*)d_in[23];
  const float* fc3b = (const float*)d_in[24];
  float* outp = (float*)d_out;

  char* ws = (char*)d_ws;
  int*      idx   = (int*)    (ws);
  float4*   spk   = (float4*) (ws + (size_t)1408 * 1024);
  _Float16* W2A   = (_Float16*)(ws + (size_t)1664 * 1024);
  float*    c0    = (float*)  (ws + (size_t)1728 * 1024);
  float*    pmax  = (float*)  (ws + (size_t)1732 * 1024);
  int*      cellS = (int*)    (ws + (size_t)1764 * 1024);
  int*      cnt   = (int*)    (ws + (size_t)1800 * 1024);   // cnt + cnt2
  int*      cnt2  = cnt + BATCH * NCELL;
  _Float16* WFB   = (_Float16*)(ws + (size_t)1864 * 1024);  // 73.7 KB
  float*    v     = (float*)  (ws + (size_t)2 * 1048576);
  float*    kh    = (float*)  (ws + (size_t)6656 * 1024);
  float*    qh    = (float*)  (ws + (size_t)24064 * 1024);
  float*    act   = (float*)  (ws + (size_t)41472 * 1024);

  k_zero<<<(2 * BATCH * NCELL + 255) / 256, 256, 0, stream>>>(cnt);
  k_hist<<<(TOTAL + 255) / 256, 256, 0, stream>>>(pts, cnt);
  k_scan<<<BATCH, 256, 0, stream>>>(cnt, cellS);
  k_scatter<<<(TOTAL + 255) / 256, 256, 0, stream>>>(pts, cnt2, cellS, spk);
  k_conv<<<(TOTAL * 64 + 255) / 256, 256, 0, stream>>>(spk, conv_w, conv_b, act);
  k_knn<<<TOTAL / 4, 256, 0, stream>>>(spk, cellS, idx);

  for (int layer = 0; layer < 2; layer++) {
    int base = 3 + layer * 9;
    const float* qkvw = (const float*)d_in[base + 0];
    const float* pw1  = (const float*)d_in[base + 1];
    const float* pb1  = (const float*)d_in[base + 2];
    const float* pw2  = (const float*)d_in[base + 3];
    const float* pb2  = (const float*)d_in[base + 4];
    const float* aw1  = (const float*)d_in[base + 5];
    const float* ab1  = (const float*)d_in[base + 6];
    const float* aw2  = (const float*)d_in[base + 7];
    const float* ab2  = (const float*)d_in[base + 8];
    k_w2<<<65, 256, 0, stream>>>(pw2, pb2, aw1, W2A, c0);
    k_fold<<<144, 256, 0, stream>>>(qkvw, aw1, WFB);
    k_pre2<<<TOTAL / 64, 256, 0, stream>>>((const float*)act,
                                           (const f16x4*)WFB, c0, ab1,
                                           v, kh, qh);
    k_attn<<<TOTAL / 8, 256, 0, stream>>>(
        spk, v, idx, kh, qh, pw1, pb1, pw2, pb2, W2A, aw2, ab2, act);
  }
  k_pool<<<BATCH * 64, 256, 0, stream>>>(act, pmax);
  k_final2<<<BATCH, 256, 0, stream>>>(pmax, fc1w, fc1b, fc3w, fc3b, outp);
}

// Round 9
// 450.488 us; speedup vs baseline: 1.6328x; 1.6328x over previous
//
#include <hip/hip_runtime.h>
#include <cstdint>
#include <cstddef>

#define KNB 20
#define NPTS 8192
#define BATCH 2
#define TOTAL (BATCH * NPTS)
#define NCELL 4096               // 16^3 grid per batch
#define SENT 0x7F800000FFFFFFFFULL  // d2=+inf, low=~0 (u64-max real key bound)
#define CAP 1024                 // per-wave candidate buffer (ints)

typedef _Float16 f16x4 __attribute__((ext_vector_type(4)));
typedef float f32x4 __attribute__((ext_vector_type(4)));

// ---------------------------------------------------------------------------
// Grid build (per batch, 16^3 cells, counting sort). All tiny (~25 µs).
// ---------------------------------------------------------------------------
__global__ __launch_bounds__(256) void k_zero(int* __restrict__ cnt) {
  int g = blockIdx.x * 256 + threadIdx.x;
  if (g < 2 * BATCH * NCELL) cnt[g] = 0;   // cnt + cnt2, contiguous
}

__global__ __launch_bounds__(256) void k_hist(const float* __restrict__ pts,
                                              int* __restrict__ cnt) {
  int p = blockIdx.x * 256 + threadIdx.x;
  if (p >= TOTAL) return;
  int b = p >> 13;
  int cx = min(15, (int)(pts[p * 3 + 0] * 16.f));
  int cy = min(15, (int)(pts[p * 3 + 1] * 16.f));
  int cz = min(15, (int)(pts[p * 3 + 2] * 16.f));
  atomicAdd(&cnt[b * NCELL + (cz * 16 + cy) * 16 + cx], 1);
}

__global__ __launch_bounds__(256) void k_scan(const int* __restrict__ cnt,
                                              int* __restrict__ cellStart) {
  __shared__ int ls[256];
  int b = blockIdx.x, t = threadIdx.x;
  const int* c = cnt + b * NCELL;
  int* cs = cellStart + b * (NCELL + 1);
  int base = t * 16;
  int s = 0;
#pragma unroll
  for (int i = 0; i < 16; i++) s += c[base + i];
  ls[t] = s;
  __syncthreads();
  for (int off = 1; off < 256; off <<= 1) {
    int v = (t >= off) ? ls[t - off] : 0;
    __syncthreads();
    ls[t] += v;
    __syncthreads();
  }
  int run = ls[t] - s;                  // exclusive prefix
#pragma unroll
  for (int i = 0; i < 16; i++) { cs[base + i] = run; run += c[base + i]; }
  if (t == 255) cs[NCELL] = run;        // sentinel = NPTS
}

// k_scatter: packed (x,y,z,orig_local_idx) per sorted slot. Coordinates are
// bit-exact copies of pts, so all downstream arithmetic is unchanged.
__global__ __launch_bounds__(256) void k_scatter(
    const float* __restrict__ pts, int* __restrict__ cnt2,
    const int* __restrict__ cellStart, float4* __restrict__ spk) {
  int p = blockIdx.x * 256 + threadIdx.x;
  if (p >= TOTAL) return;
  int b = p >> 13, pl = p & (NPTS - 1);
  float x = pts[p * 3 + 0], y = pts[p * 3 + 1], z = pts[p * 3 + 2];
  int cx = min(15, (int)(x * 16.f));
  int cy = min(15, (int)(y * 16.f));
  int cz = min(15, (int)(z * 16.f));
  int cell = (cz * 16 + cy) * 16 + cx;
  int pos = cellStart[b * (NCELL + 1) + cell] + atomicAdd(&cnt2[b * NCELL + cell], 1);
  spk[(size_t)b * NPTS + pos] = make_float4(x, y, z, __int_as_float(pl));
}

// ---------------------------------------------------------------------------
// K1: pointwise conv 3->64 + relu — SORTED space.
// ---------------------------------------------------------------------------
__global__ __launch_bounds__(256) void k_conv(const float4* __restrict__ spk,
                                              const float* __restrict__ w,
                                              const float* __restrict__ b,
                                              float* __restrict__ x0) {
  int gid = blockIdx.x * 256 + threadIdx.x;
  if (gid >= TOTAL * 64) return;
  int p = gid >> 6, c = gid & 63;
  float4 pp = spk[p];
  float acc = b[c] + pp.x * w[c] + pp.y * w[64 + c] + pp.z * w[128 + c];
  x0[gid] = fmaxf(acc, 0.f);
}

// ---------------------------------------------------------------------------
// K2: GRID KNN (R1-proven cascade) — SORTED-space queries and outputs.
//  Key = [d2:32][origid:13][sortpos:13] -> exact lax.top_k order.
//  R9: grid passes use a 16-deep per-lane list (INS16) — EXACT because the
//  balanced scatter gives each lane <= CAP/64 = 16 candidates, so depth 16
//  is the lane's COMPLETE candidate list (merge = top-20 of union of
//  complete lists; tau19 uses only lane minima, depth-independent).
//  Fallback keeps depth 20 (a lane there may hold up to 20 of the top-20).
// ---------------------------------------------------------------------------
__global__ __launch_bounds__(256) void k_knn(
    const float4* __restrict__ spk, const int* __restrict__ cellStart,
    int* __restrict__ idxbuf) {
  __shared__ int s_cand[4][CAP];       // 16 KB
  int tid = threadIdx.x;
  int wv = tid >> 6, lane = tid & 63;
  int q = blockIdx.x * 4 + wv;         // SORTED index
  int bq = q >> 13;
  const float4* bp = spk + (size_t)bq * NPTS;
  const int* cs = cellStart + bq * (NCELL + 1);
  float4 qp = bp[q & (NPTS - 1)];
  float qx = qp.x, qy = qp.y, qz = qp.z;
  int cx = min(15, (int)(qx * 16.f));
  int cy = min(15, (int)(qy * 16.f));
  int cz = min(15, (int)(qz * 16.f));

  unsigned long long key[KNB];
  float tau19 = __uint_as_float(0x7F800000u);
  int pass_ok = 0;

#define INS(KK)                                                              \
  if ((KK) < key[KNB - 1]) {                                                 \
    _Pragma("unroll")                                                        \
    for (int j = KNB - 1; j >= 0; j--) {                                     \
      bool cj = (KK) < key[j];                                               \
      bool cjm1 = (j > 0) && ((KK) < key[j - 1]);                            \
      if (cj) key[j] = cjm1 ? key[j - 1] : (KK);                             \
    }                                                                        \
  }

#define INS16(KK)                                                            \
  if ((KK) < key[15]) {                                                      \
    _Pragma("unroll")                                                        \
    for (int j = 15; j >= 0; j--) {                                          \
      bool cj = (KK) < key[j];                                               \
      bool cjm1 = (j > 0) && ((KK) < key[j - 1]);                            \
      if (cj) key[j] = cjm1 ? key[j - 1] : (KK);                             \
    }                                                                        \
  }

#define PASS(RR, WW, NRR, BOUND)                                             \
  {                                                                          \
    _Pragma("unroll")                                                        \
    for (int j = 0; j < KNB; j++) key[j] = SENT;                             \
    int sv = 0, lenv = 0;                                                    \
    if (lane < (NRR)) {                                                      \
      int dz = lane / (WW) - (RR), dy = lane % (WW) - (RR);                  \
      int z = cz + dz, y = cy + dy;                                          \
      if ((unsigned)z < 16u && (unsigned)y < 16u) {                          \
        int x0 = cx - (RR); if (x0 < 0) x0 = 0;                              \
        int x1 = cx + (RR); if (x1 > 15) x1 = 15;                            \
        int rb = (z * 16 + y) * 16;                                          \
        sv = cs[rb + x0];                                                    \
        lenv = cs[rb + x1 + 1] - sv;                                         \
      }                                                                      \
    }                                                                        \
    int pre = lenv;                                                          \
    _Pragma("unroll")                                                        \
    for (int off = 1; off < 64; off <<= 1) {                                 \
      int o = __shfl_up(pre, off);                                           \
      if (lane >= off) pre += o;                                             \
    }                                                                        \
    int T = __shfl(pre, 63);                                                 \
    int excl = pre - lenv;                                                   \
    asm volatile("s_waitcnt lgkmcnt(0)" ::: "memory"); /* WAR vs prior pass */\
    for (int k2 = 0; k2 < lenv; k2++) {                                      \
      int wpos = excl + k2;                                                  \
      if (wpos < CAP) s_cand[wv][wpos] = sv + k2;                            \
    }                                                                        \
    asm volatile("s_waitcnt lgkmcnt(0)" ::: "memory"); /* RAW: writes done */\
    int Tc = T < CAP ? T : CAP;                                              \
    for (int t = lane; t < Tc; t += 64) {                                    \
      int ci = s_cand[wv][t];                                                \
      float4 pk = bp[ci];                                                    \
      float dxv = qx - pk.x, dyv = qy - pk.y, dzv = qz - pk.z;               \
      float d2 = __fadd_rn(__fadd_rn(__fmul_rn(dxv, dxv),                    \
                                     __fmul_rn(dyv, dyv)),                   \
                           __fmul_rn(dzv, dzv));                             \
      unsigned long long kk =                                                \
          ((unsigned long long)__float_as_uint(d2) << 32) |                  \
          ((unsigned)__float_as_uint(pk.w) << 13) | (unsigned)ci;            \
      INS16(kk)                                                              \
    }                                                                        \
    float h = __uint_as_float((unsigned)(key[0] >> 32));                     \
    _Pragma("unroll")                                                        \
    for (int kk2 = 2; kk2 <= 64; kk2 <<= 1) {                                \
      _Pragma("unroll")                                                      \
      for (int j = kk2 >> 1; j > 0; j >>= 1) {                               \
        float o = __shfl_xor(h, j);                                          \
        bool up = ((lane & kk2) == 0);                                       \
        bool lower = ((lane & j) == 0);                                      \
        bool takeMin = (up == lower);                                        \
        bool lt = h < o;                                                     \
        h = (takeMin == lt) ? h : o;                                         \
      }                                                                      \
    }                                                                        \
    tau19 = __shfl(h, 19);                                                   \
    pass_ok = (T <= CAP) && (tau19 < (BOUND));                               \
  }

  float fx = fminf(qx, 1.f - qx), fy = fminf(qy, 1.f - qy),
        fz = fminf(qz, 1.f - qz);
  int nearf = (fx < 0.13f) + (fy < 0.13f) + (fz < 0.13f);

  if (nearf < 2) PASS(2, 5, 25, 0.0155f)
  if (!pass_ok)  PASS(3, 7, 49, 0.0351f)
#undef PASS

  if (!pass_ok) {
    // exact rescan of all 8192 with tau filter, from scratch (depth 20).
#pragma unroll
    for (int j = 0; j < KNB; j++) key[j] = SENT;
    for (int g = 0; g < 32; g++) {
      int i0 = g * 256 + lane * 4;
#pragma unroll
      for (int c = 0; c < 4; c++) {
        float4 pk = bp[i0 + c];
        float dxv = qx - pk.x, dyv = qy - pk.y, dzv = qz - pk.z;
        float d2 = __fadd_rn(__fadd_rn(__fmul_rn(dxv, dxv),
                                       __fmul_rn(dyv, dyv)),
                             __fmul_rn(dzv, dzv));
        if (d2 <= tau19) {
          unsigned long long kk =
              ((unsigned long long)__float_as_uint(d2) << 32) |
              ((unsigned)__float_as_uint(pk.w) << 13) | (unsigned)(i0 + c);
          INS(kk)
        }
      }
    }
  }
#undef INS
#undef INS16

  int bqoff = bq * NPTS;
  for (int step = 0; step < KNB; step++) {
    unsigned long long p = key[0];
    unsigned long long m = p;
#pragma unroll
    for (int off = 32; off >= 1; off >>= 1) {
      unsigned long long o = __shfl_xor(m, off);
      m = (o < m) ? o : m;
    }
    if (lane == 0) idxbuf[q * KNB + step] = bqoff + (int)(m & 0x1FFFULL);
    if (p == m) {
#pragma unroll
      for (int j = 0; j < KNB - 1; j++) key[j] = key[j + 1];
      key[KNB - 1] = SENT;
    }
  }
}

// ---------------------------------------------------------------------------
// K3: fused per-layer weight fold (R9: k_w2 + k_fold in one dispatch).
//  blocks 0..64  : W2A = pw2@aw1_bot (f16 A-frags) and c0 = pb2@aw1_bot
//  blocks 65..208: WFB = folded kh|qh|v weights (f16 B-frags)
// ---------------------------------------------------------------------------
__global__ __launch_bounds__(256) void k_wf(const float* __restrict__ pw2,
                                            const float* __restrict__ pb2,
                                            const float* __restrict__ aw1,
                                            const float* __restrict__ qkvw,
                                            _Float16* __restrict__ W2A,
                                            float* __restrict__ c0,
                                            _Float16* __restrict__ WFB) {
  int b = blockIdx.x;
  if (b < 65) {
    int h = b, c = threadIdx.x;
    float a = 0.f;
    if (h < 64) {
#pragma unroll 8
      for (int j = 0; j < 64; j++)
        a += pw2[h * 64 + j] * aw1[(size_t)(64 + j) * 256 + c];
      int mt = c >> 4, lo = c & 15;
      int ks = h >> 4, hi = (h >> 2) & 3, el = h & 3;
      W2A[(size_t)(((mt * 4 + ks) * 64) + hi * 16 + lo) * 4 + el] = (_Float16)a;
    } else {
#pragma unroll 8
      for (int j = 0; j < 64; j++)
        a += pb2[j] * aw1[(size_t)(64 + j) * 256 + c];
      c0[c] = a;
    }
  } else {
    int id = (b - 65) * 256 + threadIdx.x;   // 144 blocks x 256 = 36864
    int h = id & 63, c = id >> 6;
    float a = 0.f;
    if (c < 256) {
#pragma unroll 8
      for (int j = 0; j < 64; j++)
        a += qkvw[h * 192 + 64 + j] * aw1[(size_t)j * 256 + c];
    } else if (c < 512) {
      int cc = c - 256;
#pragma unroll 8
      for (int j = 0; j < 64; j++)
        a += qkvw[h * 192 + j] * aw1[(size_t)j * 256 + cc];
    } else {
      a = qkvw[h * 192 + 128 + (c - 512)];
    }
    int nt = c >> 4, lo = c & 15, ks = h >> 4, hi = (h >> 2) & 3, e = h & 3;
    WFB[(size_t)(((nt * 4 + ks) * 64) + hi * 16 + lo) * 4 + e] = (_Float16)a;
  }
}

// ---------------------------------------------------------------------------
// K3b: k_pre2 — MFMA GEMM producing kh|qh|v (R3-proven, unchanged).
// ---------------------------------------------------------------------------
__global__ __launch_bounds__(256) void k_pre2(const float* __restrict__ x,
                                              const f16x4* __restrict__ WFB,
                                              const float* __restrict__ c0,
                                              const float* __restrict__ ab1,
                                              float* __restrict__ v,
                                              float* __restrict__ kh,
                                              float* __restrict__ qh) {
  int tid = threadIdx.x;
  int wv = tid >> 6, lane = tid & 63;
  int mt = blockIdx.x * 4 + wv;
  int m0 = mt * 16;
  int lo = lane & 15, hi = lane >> 4;

  f16x4 af[4];
#pragma unroll
  for (int ks = 0; ks < 4; ks++) {
    float4 xv = *(const float4*)&x[(size_t)(m0 + lo) * 64 + ks * 16 + hi * 4];
    f16x4 a;
    a[0] = (_Float16)xv.x; a[1] = (_Float16)xv.y;
    a[2] = (_Float16)xv.z; a[3] = (_Float16)xv.w;
    af[ks] = a;
  }

#pragma unroll 4
  for (int nt = 0; nt < 36; nt++) {
    f32x4 acc = {0.f, 0.f, 0.f, 0.f};
#pragma unroll
    for (int ks = 0; ks < 4; ks++)
      acc = __builtin_amdgcn_mfma_f32_16x16x16f16(af[ks],
                                                  WFB[(nt * 4 + ks) * 64 + lane],
                                                  acc, 0, 0, 0);
    if (nt < 16) {
      int col = nt * 16 + lo;
#pragma unroll
      for (int r = 0; r < 4; r++)
        kh[(size_t)(m0 + hi * 4 + r) * 256 + col] = acc[r];
    } else if (nt < 32) {
      int col = (nt - 16) * 16 + lo;
      float bv = c0[col] + ab1[col];
#pragma unroll
      for (int r = 0; r < 4; r++)
        qh[(size_t)(m0 + hi * 4 + r) * 256 + col] = acc[r] + bv;
    } else {
      int col = (nt - 32) * 16 + lo;
#pragma unroll
      for (int r = 0; r < 4; r++)
        v[(size_t)(m0 + hi * 4 + r) * 64 + col] = acc[r];
    }
  }
}

// ---------------------------------------------------------------------------
// K4: attention — R7-proven version, reverted byte-for-byte (R8 post-mortem:
//  wave64 VGPR pool is ~256/SIMD-slot; 64 regs = 4 waves is this structure's
//  optimum — 6-wave forcing spills (R8, 40 regs, 71MB scratch), and the
//  low-reg serialized variant trades away per-wave MLP (8->2 outstanding
//  kh loads). Do not re-tune launch bounds here.
// ---------------------------------------------------------------------------
__global__ __launch_bounds__(256, 4) void k_attn(
    const float4* __restrict__ spk4, const float* __restrict__ v,
    const int* __restrict__ idxbuf, const float* __restrict__ kh,
    const float* __restrict__ qh,
    const float* __restrict__ pw1, const float* __restrict__ pb1,
    const float* __restrict__ pw2, const float* __restrict__ pb2,
    const _Float16* __restrict__ W2A,
    const float* __restrict__ aw2, const float* __restrict__ ab2,
    float* __restrict__ xout) {
  __shared__ __align__(16) _Float16 s_t1h[4][1280];  // 10 KB: 20 rows x 64
  __shared__ float s_sim[4][2][KNB];
  __shared__ int   s_nb[4][2][24];

  int tid = threadIdx.x;
  int wv = tid >> 6, lane = tid & 63;
  int q0 = blockIdx.x * 8 + wv * 2;          // this wave: queries q0, q0+1
  int lo = lane & 15, hi = lane >> 4;

  if (lane < KNB) {
    s_nb[wv][0][lane] = idxbuf[q0 * KNB + lane];
    s_nb[wv][1][lane] = idxbuf[(q0 + 1) * KNB + lane];
  }
  float4 qpa = spk4[q0];
  float4 qpb = spk4[q0 + 1];
  asm volatile("s_waitcnt lgkmcnt(0)" ::: "memory");  // s_nb visible to wave

  float w1x = pw1[lane], w1y = pw1[64 + lane], w1z = pw1[128 + lane];
  float b1h = pb1[lane];

  // A: per query: stage t1 (f16, swizzled, 20 rows) -> read frags -> regs.
  // Same buffer reused; lgkmcnt(0) gives RAW after writes, WAR after reads.
  f16x4 bf[2][2][4];
#pragma unroll
  for (int qq = 0; qq < 2; qq++) {
    float px = qq ? qpb.x : qpa.x;
    float py = qq ? qpb.y : qpa.y;
    float pz = qq ? qpb.z : qpa.z;
#pragma unroll
    for (int n = 0; n < KNB; n++) {
      int g = s_nb[wv][qq][n];
      float4 np = spk4[g];
      float t1n = fmaxf(b1h + (px - np.x) * w1x + (py - np.y) * w1y +
                            (pz - np.z) * w1z, 0.f);
      s_t1h[wv][(n * 64 + lane) ^ ((n & 7) << 3)] = (_Float16)t1n;
    }
    asm volatile("s_waitcnt lgkmcnt(0)" ::: "memory");  // writes visible
    // B-frags: lane l -> B[k=ks*16+4*hi+e][nb=nt*16+lo]; cols>=20 = 0.
#pragma unroll
    for (int ks = 0; ks < 4; ks++) {
      int i0 = ((lo * 64) + ks * 16 + hi * 4) ^ ((lane & 7) << 3);
      bf[qq][0][ks] = *(const f16x4*)&s_t1h[wv][i0];
      if (lo < 4) {
        int i1 = (((16 + lo) * 64) + ks * 16 + hi * 4) ^ ((lane & 7) << 3);
        bf[qq][1][ks] = *(const f16x4*)&s_t1h[wv][i1];
      } else {
        f16x4 z = {(_Float16)0.f, (_Float16)0.f, (_Float16)0.f, (_Float16)0.f};
        bf[qq][1][ks] = z;
      }
    }
    asm volatile("s_waitcnt lgkmcnt(0)" ::: "memory");  // reads done (WAR)
  }

  const f16x4* W2A4 = (const f16x4*)W2A;
  int g0a = s_nb[wv][0][lo];
  int g1a = s_nb[wv][0][(lo < 4) ? (16 + lo) : 0];  // lo>=4: dummy (isolated)
  int g0b = s_nb[wv][1][lo];
  int g1b = s_nb[wv][1][(lo < 4) ? (16 + lo) : 0];
  const float* khr0a = &kh[(size_t)g0a * 256];
  const float* khr1a = &kh[(size_t)g1a * 256];
  const float* khr0b = &kh[(size_t)g0b * 256];
  const float* khr1b = &kh[(size_t)g1b * 256];
  const float* qhra  = &qh[(size_t)q0 * 256];
  const float* qhrb  = &qh[(size_t)(q0 + 1) * 256];
  float sim0a = 0.f, sim1a = 0.f, sim0b = 0.f, sim1b = 0.f;

#pragma unroll 2
  for (int mt = 0; mt < 16; mt++) {
    f32x4 a0a = {0.f, 0.f, 0.f, 0.f}, a1a = {0.f, 0.f, 0.f, 0.f};
    f32x4 a0b = {0.f, 0.f, 0.f, 0.f}, a1b = {0.f, 0.f, 0.f, 0.f};
#pragma unroll
    for (int ks = 0; ks < 4; ks++) {
      f16x4 af = W2A4[(mt * 4 + ks) * 64 + lane];
      a0a = __builtin_amdgcn_mfma_f32_16x16x16f16(af, bf[0][0][ks], a0a, 0, 0, 0);
      a1a = __builtin_amdgcn_mfma_f32_16x16x16f16(af, bf[0][1][ks], a1a, 0, 0, 0);
      a0b = __builtin_amdgcn_mfma_f32_16x16x16f16(af, bf[1][0][ks], a0b, 0, 0, 0);
      a1b = __builtin_amdgcn_mfma_f32_16x16x16f16(af, bf[1][1][ks], a1b, 0, 0, 0);
    }
    int cb = mt * 16 + hi * 4;
    float4 w24 = *(const float4*)&aw2[cb];
    {
      float4 kh0 = *(const float4*)&khr0a[cb];
      float4 kh1 = *(const float4*)&khr1a[cb];
      float4 qh4 = *(const float4*)&qhra[cb];
      sim0a += fmaxf(a0a[0] + qh4.x - kh0.x, 0.f) * w24.x +
               fmaxf(a0a[1] + qh4.y - kh0.y, 0.f) * w24.y +
               fmaxf(a0a[2] + qh4.z - kh0.z, 0.f) * w24.z +
               fmaxf(a0a[3] + qh4.w - kh0.w, 0.f) * w24.w;
      sim1a += fmaxf(a1a[0] + qh4.x - kh1.x, 0.f) * w24.x +
               fmaxf(a1a[1] + qh4.y - kh1.y, 0.f) * w24.y +
               fmaxf(a1a[2] + qh4.z - kh1.z, 0.f) * w24.z +
               fmaxf(a1a[3] + qh4.w - kh1.w, 0.f) * w24.w;
    }
    {
      float4 kh0 = *(const float4*)&khr0b[cb];
      float4 kh1 = *(const float4*)&khr1b[cb];
      float4 qh4 = *(const float4*)&qhrb[cb];
      sim0b += fmaxf(a0b[0] + qh4.x - kh0.x, 0.f) * w24.x +
               fmaxf(a0b[1] + qh4.y - kh0.y, 0.f) * w24.y +
               fmaxf(a0b[2] + qh4.z - kh0.z, 0.f) * w24.z +
               fmaxf(a0b[3] + qh4.w - kh0.w, 0.f) * w24.w;
      sim1b += fmaxf(a1b[0] + qh4.x - kh1.x, 0.f) * w24.x +
               fmaxf(a1b[1] + qh4.y - kh1.y, 0.f) * w24.y +
               fmaxf(a1b[2] + qh4.z - kh1.z, 0.f) * w24.z +
               fmaxf(a1b[3] + qh4.w - kh1.w, 0.f) * w24.w;
    }
  }
  // reduce over hi (XOR 16/32 keeps lo fixed; lo>=4 garbage isolated).
  sim0a += __shfl_xor(sim0a, 16); sim0a += __shfl_xor(sim0a, 32);
  sim1a += __shfl_xor(sim1a, 16); sim1a += __shfl_xor(sim1a, 32);
  sim0b += __shfl_xor(sim0b, 16); sim0b += __shfl_xor(sim0b, 32);
  sim1b += __shfl_xor(sim1b, 16); sim1b += __shfl_xor(sim1b, 32);
  float ab2v = ab2[0];
  if (lane < 16) s_sim[wv][0][lane] = sim0a + ab2v;
  if (lane < 4)  s_sim[wv][0][16 + lane] = sim1a + ab2v;
  if (lane < 16) s_sim[wv][1][lane] = sim0b + ab2v;
  if (lane < 4)  s_sim[wv][1][16 + lane] = sim1b + ab2v;
  asm volatile("s_waitcnt lgkmcnt(0)" ::: "memory");  // s_sim visible

  // C: per query: softmax; out = sum an*v[g] + (sum an*t1_n)@pw2 + pb2.
  // t1_n recomputed bit-identically (same inputs/ops as phase A).
#define RL(x, l) __uint_as_float(__builtin_amdgcn_readlane(__float_as_uint(x), (l)))
#pragma unroll
  for (int qq = 0; qq < 2; qq++) {
    float px = qq ? qpb.x : qpa.x;
    float py = qq ? qpb.y : qpa.y;
    float pz = qq ? qpb.z : qpa.z;
    float mx = -3.402823466e38f;
#pragma unroll
    for (int n = 0; n < KNB; n++) mx = fmaxf(mx, s_sim[wv][qq][n]);
    float sum = 0.f;
#pragma unroll
    for (int n = 0; n < KNB; n++) sum += expf(s_sim[wv][qq][n] - mx);
    float inv = 1.f / sum;
    float o = 0.f;
    float sac = 0.f;
#pragma unroll
    for (int n = 0; n < KNB; n++) {
      float an = expf(s_sim[wv][qq][n] - mx) * inv;
      int g = s_nb[wv][qq][n];
      o += an * v[(size_t)g * 64 + lane];
      float4 np = spk4[g];
      float t1n = fmaxf(b1h + (px - np.x) * w1x + (py - np.y) * w1y +
                            (pz - np.z) * w1z, 0.f);
      sac += an * t1n;
    }
    float r = pb2[lane];
#pragma unroll 8
    for (int j = 0; j < 64; j++) r += RL(sac, j) * pw2[j * 64 + lane];
    xout[(size_t)(q0 + qq) * 64 + lane] = o + r;
  }
#undef RL
}

// ---------------------------------------------------------------------------
// K5a/K5b: parallel max-pool + head (order-invariant; sorted act OK).
// ---------------------------------------------------------------------------
__global__ __launch_bounds__(256) void k_pool(const float* __restrict__ x,
                                              float* __restrict__ pmax) {
  __shared__ float red[4][64];
  int b = blockIdx.x >> 6, blk = blockIdx.x & 63;
  int tid = threadIdx.x;
  int c = tid & 63, pg = tid >> 6;
  int p0 = blk * 128;
  float mx = -3.402823466e38f;
  for (int p = pg; p < 128; p += 4)
    mx = fmaxf(mx, x[((size_t)b * NPTS + p0 + p) * 64 + c]);
  red[pg][c] = mx;
  __syncthreads();
  if (tid < 64)
    pmax[(size_t)blockIdx.x * 64 + c] =
        fmaxf(fmaxf(red[0][c], red[1][c]), fmaxf(red[2][c], red[3][c]));
}

__global__ __launch_bounds__(256) void k_final2(const float* __restrict__ pmax,
                                                const float* __restrict__ fc1w,
                                                const float* __restrict__ fc1b,
                                                const float* __restrict__ fc3w,
                                                const float* __restrict__ fc3b,
                                                float* __restrict__ out) {
  __shared__ float red[4][64];
  __shared__ float m[64];
  __shared__ float h1[32];
  int b = blockIdx.x;
  int tid = threadIdx.x;
  int c = tid & 63, pg = tid >> 6;
  float mx = -3.402823466e38f;
  for (int blk = pg; blk < 64; blk += 4)
    mx = fmaxf(mx, pmax[(size_t)(b * 64 + blk) * 64 + c]);
  red[pg][c] = mx;
  __syncthreads();
  if (tid < 64)
    m[c] = fmaxf(fmaxf(red[0][c], red[1][c]), fmaxf(red[2][c], red[3][c]));
  __syncthreads();
  if (tid < 32) {
    float a = fc1b[tid];
#pragma unroll 8
    for (int k = 0; k < 64; k++) a += m[k] * fc1w[k * 32 + tid];
    h1[tid] = fmaxf(a, 0.f);
  }
  __syncthreads();
  if (tid < 3) {
    float a = fc3b[tid];
#pragma unroll
    for (int k = 0; k < 32; k++) a += h1[k] * fc3w[k * 3 + tid];
    out[b * 3 + tid] = a;
  }
}

// ---------------------------------------------------------------------------
// Workspace (peak ~44.8 MB):
//   idx @ 0 (1.31MB) | spk @ 1408KB (256KB; LIVE through both layers)
//   W2A @ 1664KB (32KB f16 frags) | c0 @ 1728KB (1KB) | pmax @ 1732KB (32KB)
//   cellStart @ 1764KB (33KB) | cnt+cnt2 @ 1800KB (64KB)
//   WFB @ 1864KB (73.7KB f16 frags)
//   v @ 2MB (4.2MB) | kh @ 6.5MB (16.8MB) | qh @ 23.5MB (16.8MB)
//   act @ 40.5MB (4.2MB)
// ---------------------------------------------------------------------------
extern "C" void kernel_launch(void* const* d_in, const int* in_sizes, int n_in,
                              void* d_out, int out_size, void* d_ws,
                              size_t ws_size, hipStream_t stream) {
  const float* pts    = (const float*)d_in[0];
  const float* conv_w = (const float*)d_in[1];
  const float* conv_b = (const float*)d_in[2];
  const float* fc1w = (const float*)d_in[21];
  const float* fc1b = (const float*)d_in[22];
  const float* fc3w = (const float*)d_in[23];
  const float* fc3b = (const float*)d_in[24];
  float* outp = (float*)d_out;

  char* ws = (char*)d_ws;
  int*      idx   = (int*)    (ws);
  float4*   spk   = (float4*) (ws + (size_t)1408 * 1024);
  _Float16* W2A   = (_Float16*)(ws + (size_t)1664 * 1024);
  float*    c0    = (float*)  (ws + (size_t)1728 * 1024);
  float*    pmax  = (float*)  (ws + (size_t)1732 * 1024);
  int*      cellS = (int*)    (ws + (size_t)1764 * 1024);
  int*      cnt   = (int*)    (ws + (size_t)1800 * 1024);   // cnt + cnt2
  int*      cnt2  = cnt + BATCH * NCELL;
  _Float16* WFB   = (_Float16*)(ws + (size_t)1864 * 1024);  // 73.7 KB
  float*    v     = (float*)  (ws + (size_t)2 * 1048576);
  float*    kh    = (float*)  (ws + (size_t)6656 * 1024);
  float*    qh    = (float*)  (ws + (size_t)24064 * 1024);
  float*    act   = (float*)  (ws + (size_t)41472 * 1024);

  k_zero<<<(2 * BATCH * NCELL + 255) / 256, 256, 0, stream>>>(cnt);
  k_hist<<<(TOTAL + 255) / 256, 256, 0, stream>>>(pts, cnt);
  k_scan<<<BATCH, 256, 0, stream>>>(cnt, cellS);
  k_scatter<<<(TOTAL + 255) / 256, 256, 0, stream>>>(pts, cnt2, cellS, spk);
  k_conv<<<(TOTAL * 64 + 255) / 256, 256, 0, stream>>>(spk, conv_w, conv_b, act);
  k_knn<<<TOTAL / 4, 256, 0, stream>>>(spk, cellS, idx);

  for (int layer = 0; layer < 2; layer++) {
    int base = 3 + layer * 9;
    const float* qkvw = (const float*)d_in[base + 0];
    const float* pw1  = (const float*)d_in[base + 1];
    const float* pb1  = (const float*)d_in[base + 2];
    const float* pw2  = (const float*)d_in[base + 3];
    const float* pb2  = (const float*)d_in[base + 4];
    const float* aw1  = (const float*)d_in[base + 5];
    const float* ab1  = (const float*)d_in[base + 6];
    const float* aw2  = (const float*)d_in[base + 7];
    const float* ab2  = (const float*)d_in[base + 8];
    k_wf<<<209, 256, 0, stream>>>(pw2, pb2, aw1, qkvw, W2A, c0, WFB);
    k_pre2<<<TOTAL / 64, 256, 0, stream>>>((const float*)act,
                                           (const f16x4*)WFB, c0, ab1,
                                           v, kh, qh);
    k_attn<<<TOTAL / 8, 256, 0, stream>>>(
        spk, v, idx, kh, qh, pw1, pb1, pw2, pb2, W2A, aw2, ab2, act);
  }
  k_pool<<<BATCH * 64, 256, 0, stream>>>(act, pmax);
  k_final2<<<BATCH, 256, 0, stream>>>(pmax, fc1w, fc1b, fc3w, fc3b, outp);
}

// Round 10
// 448.745 us; speedup vs baseline: 1.6391x; 1.0039x over previous
//
#include <hip/hip_runtime.h>
#include <cstdint>
#include <cstddef>

#define KNB 20
#define NPTS 8192
#define BATCH 2
#define TOTAL (BATCH * NPTS)
#define NCELL 4096               // 16^3 grid per batch
#define SENT 0x7F800000FFFFFFFFULL  // d2=+inf, low=~0 (u64-max real key bound)
#define CAP 1024                 // per-wave candidate buffer (ints)

typedef _Float16 f16x4 __attribute__((ext_vector_type(4)));
typedef float f32x4 __attribute__((ext_vector_type(4)));

// ---------------------------------------------------------------------------
// Grid build (per batch, 16^3 cells, counting sort). All tiny (~25 µs).
// ---------------------------------------------------------------------------
__global__ __launch_bounds__(256) void k_zero(int* __restrict__ cnt) {
  int g = blockIdx.x * 256 + threadIdx.x;
  if (g < 2 * BATCH * NCELL) cnt[g] = 0;   // cnt + cnt2, contiguous
}

__global__ __launch_bounds__(256) void k_hist(const float* __restrict__ pts,
                                              int* __restrict__ cnt) {
  int p = blockIdx.x * 256 + threadIdx.x;
  if (p >= TOTAL) return;
  int b = p >> 13;
  int cx = min(15, (int)(pts[p * 3 + 0] * 16.f));
  int cy = min(15, (int)(pts[p * 3 + 1] * 16.f));
  int cz = min(15, (int)(pts[p * 3 + 2] * 16.f));
  atomicAdd(&cnt[b * NCELL + (cz * 16 + cy) * 16 + cx], 1);
}

__global__ __launch_bounds__(256) void k_scan(const int* __restrict__ cnt,
                                              int* __restrict__ cellStart) {
  __shared__ int ls[256];
  int b = blockIdx.x, t = threadIdx.x;
  const int* c = cnt + b * NCELL;
  int* cs = cellStart + b * (NCELL + 1);
  int base = t * 16;
  int s = 0;
#pragma unroll
  for (int i = 0; i < 16; i++) s += c[base + i];
  ls[t] = s;
  __syncthreads();
  for (int off = 1; off < 256; off <<= 1) {
    int v = (t >= off) ? ls[t - off] : 0;
    __syncthreads();
    ls[t] += v;
    __syncthreads();
  }
  int run = ls[t] - s;                  // exclusive prefix
#pragma unroll
  for (int i = 0; i < 16; i++) { cs[base + i] = run; run += c[base + i]; }
  if (t == 255) cs[NCELL] = run;        // sentinel = NPTS
}

// k_scatter: packed (x,y,z,orig_local_idx) per sorted slot. Coordinates are
// bit-exact copies of pts, so all downstream arithmetic is unchanged.
__global__ __launch_bounds__(256) void k_scatter(
    const float* __restrict__ pts, int* __restrict__ cnt2,
    const int* __restrict__ cellStart, float4* __restrict__ spk) {
  int p = blockIdx.x * 256 + threadIdx.x;
  if (p >= TOTAL) return;
  int b = p >> 13, pl = p & (NPTS - 1);
  float x = pts[p * 3 + 0], y = pts[p * 3 + 1], z = pts[p * 3 + 2];
  int cx = min(15, (int)(x * 16.f));
  int cy = min(15, (int)(y * 16.f));
  int cz = min(15, (int)(z * 16.f));
  int cell = (cz * 16 + cy) * 16 + cx;
  int pos = cellStart[b * (NCELL + 1) + cell] + atomicAdd(&cnt2[b * NCELL + cell], 1);
  spk[(size_t)b * NPTS + pos] = make_float4(x, y, z, __int_as_float(pl));
}

// ---------------------------------------------------------------------------
// K1: pointwise conv 3->64 + relu — SORTED space.
// ---------------------------------------------------------------------------
__global__ __launch_bounds__(256) void k_conv(const float4* __restrict__ spk,
                                              const float* __restrict__ w,
                                              const float* __restrict__ b,
                                              float* __restrict__ x0) {
  int gid = blockIdx.x * 256 + threadIdx.x;
  if (gid >= TOTAL * 64) return;
  int p = gid >> 6, c = gid & 63;
  float4 pp = spk[p];
  float acc = b[c] + pp.x * w[c] + pp.y * w[64 + c] + pp.z * w[128 + c];
  x0[gid] = fmaxf(acc, 0.f);
}

// ---------------------------------------------------------------------------
// K2: GRID KNN (R9-proven) — SORTED-space queries/outputs, INS16 grid passes.
// ---------------------------------------------------------------------------
__global__ __launch_bounds__(256) void k_knn(
    const float4* __restrict__ spk, const int* __restrict__ cellStart,
    int* __restrict__ idxbuf) {
  __shared__ int s_cand[4][CAP];       // 16 KB
  int tid = threadIdx.x;
  int wv = tid >> 6, lane = tid & 63;
  int q = blockIdx.x * 4 + wv;         // SORTED index
  int bq = q >> 13;
  const float4* bp = spk + (size_t)bq * NPTS;
  const int* cs = cellStart + bq * (NCELL + 1);
  float4 qp = bp[q & (NPTS - 1)];
  float qx = qp.x, qy = qp.y, qz = qp.z;
  int cx = min(15, (int)(qx * 16.f));
  int cy = min(15, (int)(qy * 16.f));
  int cz = min(15, (int)(qz * 16.f));

  unsigned long long key[KNB];
  float tau19 = __uint_as_float(0x7F800000u);
  int pass_ok = 0;

#define INS(KK)                                                              \
  if ((KK) < key[KNB - 1]) {                                                 \
    _Pragma("unroll")                                                        \
    for (int j = KNB - 1; j >= 0; j--) {                                     \
      bool cj = (KK) < key[j];                                               \
      bool cjm1 = (j > 0) && ((KK) < key[j - 1]);                            \
      if (cj) key[j] = cjm1 ? key[j - 1] : (KK);                             \
    }                                                                        \
  }

#define INS16(KK)                                                            \
  if ((KK) < key[15]) {                                                      \
    _Pragma("unroll")                                                        \
    for (int j = 15; j >= 0; j--) {                                          \
      bool cj = (KK) < key[j];                                               \
      bool cjm1 = (j > 0) && ((KK) < key[j - 1]);                            \
      if (cj) key[j] = cjm1 ? key[j - 1] : (KK);                             \
    }                                                                        \
  }

#define PASS(RR, WW, NRR, BOUND)                                             \
  {                                                                          \
    _Pragma("unroll")                                                        \
    for (int j = 0; j < KNB; j++) key[j] = SENT;                             \
    int sv = 0, lenv = 0;                                                    \
    if (lane < (NRR)) {                                                      \
      int dz = lane / (WW) - (RR), dy = lane % (WW) - (RR);                  \
      int z = cz + dz, y = cy + dy;                                          \
      if ((unsigned)z < 16u && (unsigned)y < 16u) {                          \
        int x0 = cx - (RR); if (x0 < 0) x0 = 0;                              \
        int x1 = cx + (RR); if (x1 > 15) x1 = 15;                            \
        int rb = (z * 16 + y) * 16;                                          \
        sv = cs[rb + x0];                                                    \
        lenv = cs[rb + x1 + 1] - sv;                                         \
      }                                                                      \
    }                                                                        \
    int pre = lenv;                                                          \
    _Pragma("unroll")                                                        \
    for (int off = 1; off < 64; off <<= 1) {                                 \
      int o = __shfl_up(pre, off);                                           \
      if (lane >= off) pre += o;                                             \
    }                                                                        \
    int T = __shfl(pre, 63);                                                 \
    int excl = pre - lenv;                                                   \
    asm volatile("s_waitcnt lgkmcnt(0)" ::: "memory"); /* WAR vs prior pass */\
    for (int k2 = 0; k2 < lenv; k2++) {                                      \
      int wpos = excl + k2;                                                  \
      if (wpos < CAP) s_cand[wv][wpos] = sv + k2;                            \
    }                                                                        \
    asm volatile("s_waitcnt lgkmcnt(0)" ::: "memory"); /* RAW: writes done */\
    int Tc = T < CAP ? T : CAP;                                              \
    for (int t = lane; t < Tc; t += 64) {                                    \
      int ci = s_cand[wv][t];                                                \
      float4 pk = bp[ci];                                                    \
      float dxv = qx - pk.x, dyv = qy - pk.y, dzv = qz - pk.z;               \
      float d2 = __fadd_rn(__fadd_rn(__fmul_rn(dxv, dxv),                    \
                                     __fmul_rn(dyv, dyv)),                   \
                           __fmul_rn(dzv, dzv));                             \
      unsigned long long kk =                                                \
          ((unsigned long long)__float_as_uint(d2) << 32) |                  \
          ((unsigned)__float_as_uint(pk.w) << 13) | (unsigned)ci;            \
      INS16(kk)                                                              \
    }                                                                        \
    float h = __uint_as_float((unsigned)(key[0] >> 32));                     \
    _Pragma("unroll")                                                        \
    for (int kk2 = 2; kk2 <= 64; kk2 <<= 1) {                                \
      _Pragma("unroll")                                                      \
      for (int j = kk2 >> 1; j > 0; j >>= 1) {                               \
        float o = __shfl_xor(h, j);                                          \
        bool up = ((lane & kk2) == 0);                                       \
        bool lower = ((lane & j) == 0);                                      \
        bool takeMin = (up == lower);                                        \
        bool lt = h < o;                                                     \
        h = (takeMin == lt) ? h : o;                                         \
      }                                                                      \
    }                                                                        \
    tau19 = __shfl(h, 19);                                                   \
    pass_ok = (T <= CAP) && (tau19 < (BOUND));                               \
  }

  float fx = fminf(qx, 1.f - qx), fy = fminf(qy, 1.f - qy),
        fz = fminf(qz, 1.f - qz);
  int nearf = (fx < 0.13f) + (fy < 0.13f) + (fz < 0.13f);

  if (nearf < 2) PASS(2, 5, 25, 0.0155f)
  if (!pass_ok)  PASS(3, 7, 49, 0.0351f)
#undef PASS

  if (!pass_ok) {
    // exact rescan of all 8192 with tau filter, from scratch (depth 20).
#pragma unroll
    for (int j = 0; j < KNB; j++) key[j] = SENT;
    for (int g = 0; g < 32; g++) {
      int i0 = g * 256 + lane * 4;
#pragma unroll
      for (int c = 0; c < 4; c++) {
        float4 pk = bp[i0 + c];
        float dxv = qx - pk.x, dyv = qy - pk.y, dzv = qz - pk.z;
        float d2 = __fadd_rn(__fadd_rn(__fmul_rn(dxv, dxv),
                                       __fmul_rn(dyv, dyv)),
                             __fmul_rn(dzv, dzv));
        if (d2 <= tau19) {
          unsigned long long kk =
              ((unsigned long long)__float_as_uint(d2) << 32) |
              ((unsigned)__float_as_uint(pk.w) << 13) | (unsigned)(i0 + c);
          INS(kk)
        }
      }
    }
  }
#undef INS
#undef INS16

  int bqoff = bq * NPTS;
  for (int step = 0; step < KNB; step++) {
    unsigned long long p = key[0];
    unsigned long long m = p;
#pragma unroll
    for (int off = 32; off >= 1; off >>= 1) {
      unsigned long long o = __shfl_xor(m, off);
      m = (o < m) ? o : m;
    }
    if (lane == 0) idxbuf[q * KNB + step] = bqoff + (int)(m & 0x1FFFULL);
    if (p == m) {
#pragma unroll
      for (int j = 0; j < KNB - 1; j++) key[j] = key[j + 1];
      key[KNB - 1] = SENT;
    }
  }
}

// ---------------------------------------------------------------------------
// K3: fused per-layer weight fold (R10).
//  WA (64KB): A-frags of the STACKED operator [W2 | Wk'] (256 x K=128):
//    ks 0..3: A[row=c][k=h]      = W2[h][c]  = (pw2@aw1_bot)[h][c]
//    ks 4..7: A[row=c][k=64+h]   = Wk'[h][c] = (Wk@aw1_top)[h][c]
//    frag addr: WA[((mt*8+ks)*64 + hi*16+lo)*4 + el]
//  c0 (f32): pb2@aw1_bot.
//  WFB (40KB): B-frags for pre2, 20 nt: qh (0..15) | v (16..19).
// ---------------------------------------------------------------------------
__global__ __launch_bounds__(256) void k_wf(const float* __restrict__ pw2,
                                            const float* __restrict__ pb2,
                                            const float* __restrict__ aw1,
                                            const float* __restrict__ qkvw,
                                            _Float16* __restrict__ WA,
                                            float* __restrict__ c0,
                                            _Float16* __restrict__ WFB) {
  int b = blockIdx.x;
  if (b < 65) {
    int h = b, c = threadIdx.x;
    float a = 0.f;
    if (h < 64) {
#pragma unroll 8
      for (int j = 0; j < 64; j++)
        a += pw2[h * 64 + j] * aw1[(size_t)(64 + j) * 256 + c];
      int mt = c >> 4, lo = c & 15;
      int ks = h >> 4, hi = (h >> 2) & 3, el = h & 3;
      WA[(size_t)(((mt * 8 + ks) * 64) + hi * 16 + lo) * 4 + el] = (_Float16)a;
    } else {
#pragma unroll 8
      for (int j = 0; j < 64; j++)
        a += pb2[j] * aw1[(size_t)(64 + j) * 256 + c];
      c0[c] = a;
    }
  } else {
    int id = (b - 65) * 256 + threadIdx.x;   // 144 blocks x 256 = 36864
    int h = id & 63, c = id >> 6;
    int ks = h >> 4, hi = (h >> 2) & 3, e = h & 3;
    float a = 0.f;
    if (c < 256) {
      // Wk' = Wk@aw1_top -> A-frag upper-K half (ks 4..7)
#pragma unroll 8
      for (int j = 0; j < 64; j++)
        a += qkvw[h * 192 + 64 + j] * aw1[(size_t)j * 256 + c];
      int mt = c >> 4, lo = c & 15;
      WA[(size_t)(((mt * 8 + 4 + ks) * 64) + hi * 16 + lo) * 4 + e] = (_Float16)a;
    } else if (c < 512) {
      int cc = c - 256;
#pragma unroll 8
      for (int j = 0; j < 64; j++)
        a += qkvw[h * 192 + j] * aw1[(size_t)j * 256 + cc];
      int nt = cc >> 4, lo = cc & 15;     // qh tiles 0..15
      WFB[(size_t)(((nt * 4 + ks) * 64) + hi * 16 + lo) * 4 + e] = (_Float16)a;
    } else {
      int cc = c - 512;
      a = qkvw[h * 192 + 128 + cc];
      int nt = 16 + (cc >> 4), lo = cc & 15;  // v tiles 16..19
      WFB[(size_t)(((nt * 4 + ks) * 64) + hi * 16 + lo) * 4 + e] = (_Float16)a;
    }
  }
}

// ---------------------------------------------------------------------------
// K3b: k_pre2 — MFMA GEMM producing qh|v only (R10: kh never materialized).
// ---------------------------------------------------------------------------
__global__ __launch_bounds__(256) void k_pre2(const float* __restrict__ x,
                                              const f16x4* __restrict__ WFB,
                                              const float* __restrict__ c0,
                                              const float* __restrict__ ab1,
                                              float* __restrict__ v,
                                              float* __restrict__ qh) {
  int tid = threadIdx.x;
  int wv = tid >> 6, lane = tid & 63;
  int mt = blockIdx.x * 4 + wv;
  int m0 = mt * 16;
  int lo = lane & 15, hi = lane >> 4;

  f16x4 af[4];
#pragma unroll
  for (int ks = 0; ks < 4; ks++) {
    float4 xv = *(const float4*)&x[(size_t)(m0 + lo) * 64 + ks * 16 + hi * 4];
    f16x4 a;
    a[0] = (_Float16)xv.x; a[1] = (_Float16)xv.y;
    a[2] = (_Float16)xv.z; a[3] = (_Float16)xv.w;
    af[ks] = a;
  }

#pragma unroll 4
  for (int nt = 0; nt < 20; nt++) {
    f32x4 acc = {0.f, 0.f, 0.f, 0.f};
#pragma unroll
    for (int ks = 0; ks < 4; ks++)
      acc = __builtin_amdgcn_mfma_f32_16x16x16f16(af[ks],
                                                  WFB[(nt * 4 + ks) * 64 + lane],
                                                  acc, 0, 0, 0);
    if (nt < 16) {
      int col = nt * 16 + lo;
      float bv = c0[col] + ab1[col];
#pragma unroll
      for (int r = 0; r < 4; r++)
        qh[(size_t)(m0 + hi * 4 + r) * 256 + col] = acc[r] + bv;
    } else {
      int col = (nt - 16) * 16 + lo;
#pragma unroll
      for (int r = 0; r < 4; r++)
        v[(size_t)(m0 + hi * 4 + r) * 64 + col] = acc[r];
    }
  }
}

// ---------------------------------------------------------------------------
// K4: attention — R10: kh gather ELIMINATED via stacked K=128 MFMA.
//  acc = [t1 ; -x_g] @ [W2 | Wk'] = t1@W2 - kh[g]; epilogue needs only
//  qh + aw2 (no gathered loads in the mt loop). Neighbor staging gathers
//  act rows (256B, L2-resident 4.2MB buf) instead of kh rows (1KB).
//  Overflow neighbors (n16-19) of BOTH queries share one a1 tile:
//  q0 on lanes lo<4, q1 on lanes lo 4..7 (qh via register select) ->
//  3 MFMA chains x 8 ks x 16 mt = 384 MFMA/wave.
//  2 queries/wave; single 5KB t1x buffer staged per query sequentially.
//  Reads act (xin), writes xout: layers PING-PONG buffers (no in-place race).
// ---------------------------------------------------------------------------
__global__ __launch_bounds__(256, 4) void k_attn(
    const float4* __restrict__ spk4, const float* __restrict__ v,
    const int* __restrict__ idxbuf, const float* __restrict__ xin,
    const float* __restrict__ qh,
    const float* __restrict__ pw1, const float* __restrict__ pb1,
    const float* __restrict__ pw2, const float* __restrict__ pb2,
    const _Float16* __restrict__ WA,
    const float* __restrict__ aw2, const float* __restrict__ ab2,
    float* __restrict__ xout) {
  __shared__ __align__(16) _Float16 s_t1x[4][2560];  // 20 KB: 20 rows x K=128
  __shared__ float s_sim[4][2][KNB];
  __shared__ int   s_nb[4][2][24];

  int tid = threadIdx.x;
  int wv = tid >> 6, lane = tid & 63;
  int q0 = blockIdx.x * 8 + wv * 2;          // this wave: queries q0, q0+1
  int lo = lane & 15, hi = lane >> 4;

  if (lane < KNB) {
    s_nb[wv][0][lane] = idxbuf[q0 * KNB + lane];
    s_nb[wv][1][lane] = idxbuf[(q0 + 1) * KNB + lane];
  }
  float4 qpa = spk4[q0];
  float4 qpb = spk4[q0 + 1];
  asm volatile("s_waitcnt lgkmcnt(0)" ::: "memory");  // s_nb visible to wave

  float w1x = pw1[lane], w1y = pw1[64 + lane], w1z = pw1[128 + lane];
  float b1h = pb1[lane];

  // A: per query: stage [t1(k=0..63); -x_g(k=64..127)] f16 swizzled -> frags.
  // Row n swizzle: idx = n*128 + (k ^ ((n&7)<<3)). Same buffer reused per
  // query; lgkmcnt(0) = RAW after writes, WAR after reads.
  f16x4 bfab[2][8];
  f16x4 bf1[8];
#pragma unroll
  for (int ks = 0; ks < 8; ks++) {
    f16x4 z = {(_Float16)0.f, (_Float16)0.f, (_Float16)0.f, (_Float16)0.f};
    bf1[ks] = z;
  }
#pragma unroll
  for (int qq = 0; qq < 2; qq++) {
    float px = qq ? qpb.x : qpa.x;
    float py = qq ? qpb.y : qpa.y;
    float pz = qq ? qpb.z : qpa.z;
#pragma unroll
    for (int n = 0; n < KNB; n++) {
      int g = s_nb[wv][qq][n];
      float4 np = spk4[g];
      float t1n = fmaxf(b1h + (px - np.x) * w1x + (py - np.y) * w1y +
                            (pz - np.z) * w1z, 0.f);
      int sw = (n & 7) << 3;
      s_t1x[wv][n * 128 + (lane ^ sw)] = (_Float16)t1n;
      float xg = xin[(size_t)g * 64 + lane];
      s_t1x[wv][n * 128 + ((64 + lane) ^ sw)] = (_Float16)(-xg);
    }
    asm volatile("s_waitcnt lgkmcnt(0)" ::: "memory");  // writes visible
    // frags: lane(lo,hi) -> B[k=ks*16+4*hi..+3][col]; col=lo for main tile.
#pragma unroll
    for (int ks = 0; ks < 8; ks++) {
      int k0 = ks * 16 + hi * 4;
      bfab[qq][ks] =
          *(const f16x4*)&s_t1x[wv][lo * 128 + (k0 ^ ((lo & 7) << 3))];
      if (qq == 0) {
        if (lo < 4) {
          int n = 16 + lo;
          bf1[ks] = *(const f16x4*)&s_t1x[wv][n * 128 + (k0 ^ ((n & 7) << 3))];
        }
      } else {
        if (lo >= 4 && lo < 8) {
          int n = 12 + lo;        // 16 + (lo-4)
          bf1[ks] = *(const f16x4*)&s_t1x[wv][n * 128 + (k0 ^ ((n & 7) << 3))];
        }
      }
    }
    asm volatile("s_waitcnt lgkmcnt(0)" ::: "memory");  // reads done (WAR)
  }

  const f16x4* WA4 = (const f16x4*)WA;
  const float* qhra = &qh[(size_t)q0 * 256];
  const float* qhrb = &qh[(size_t)(q0 + 1) * 256];
  float sim0a = 0.f, sim0b = 0.f, sim1 = 0.f;

#pragma unroll 2
  for (int mt = 0; mt < 16; mt++) {
    f32x4 a0a = {0.f, 0.f, 0.f, 0.f};
    f32x4 a0b = {0.f, 0.f, 0.f, 0.f};
    f32x4 a1  = {0.f, 0.f, 0.f, 0.f};
#pragma unroll
    for (int ks = 0; ks < 8; ks++) {
      f16x4 af = WA4[(mt * 8 + ks) * 64 + lane];
      a0a = __builtin_amdgcn_mfma_f32_16x16x16f16(af, bfab[0][ks], a0a, 0, 0, 0);
      a0b = __builtin_amdgcn_mfma_f32_16x16x16f16(af, bfab[1][ks], a0b, 0, 0, 0);
      a1  = __builtin_amdgcn_mfma_f32_16x16x16f16(af, bf1[ks],     a1,  0, 0, 0);
    }
    int cb = mt * 16 + hi * 4;
    float4 w24 = *(const float4*)&aw2[cb];
    float4 qa4 = *(const float4*)&qhra[cb];
    float4 qb4 = *(const float4*)&qhrb[cb];
    sim0a += fmaxf(a0a[0] + qa4.x, 0.f) * w24.x +
             fmaxf(a0a[1] + qa4.y, 0.f) * w24.y +
             fmaxf(a0a[2] + qa4.z, 0.f) * w24.z +
             fmaxf(a0a[3] + qa4.w, 0.f) * w24.w;
    sim0b += fmaxf(a0b[0] + qb4.x, 0.f) * w24.x +
             fmaxf(a0b[1] + qb4.y, 0.f) * w24.y +
             fmaxf(a0b[2] + qb4.z, 0.f) * w24.z +
             fmaxf(a0b[3] + qb4.w, 0.f) * w24.w;
    float4 q14;                       // register select: q0 rows on lo<4
    q14.x = (lo < 4) ? qa4.x : qb4.x; q14.y = (lo < 4) ? qa4.y : qb4.y;
    q14.z = (lo < 4) ? qa4.z : qb4.z; q14.w = (lo < 4) ? qa4.w : qb4.w;
    sim1  += fmaxf(a1[0] + q14.x, 0.f) * w24.x +
             fmaxf(a1[1] + q14.y, 0.f) * w24.y +
             fmaxf(a1[2] + q14.z, 0.f) * w24.z +
             fmaxf(a1[3] + q14.w, 0.f) * w24.w;
  }
  // reduce over hi (XOR 16/32 keeps lo fixed; garbage lanes isolated).
  sim0a += __shfl_xor(sim0a, 16); sim0a += __shfl_xor(sim0a, 32);
  sim0b += __shfl_xor(sim0b, 16); sim0b += __shfl_xor(sim0b, 32);
  sim1  += __shfl_xor(sim1, 16);  sim1  += __shfl_xor(sim1, 32);
  float ab2v = ab2[0];
  if (lane < 16) s_sim[wv][0][lane] = sim0a + ab2v;
  if (lane < 16) s_sim[wv][1][lane] = sim0b + ab2v;
  if (lane < 4)       s_sim[wv][0][16 + lane] = sim1 + ab2v;       // q0 ovf
  else if (lane < 8)  s_sim[wv][1][12 + lane] = sim1 + ab2v;       // q1 ovf
  asm volatile("s_waitcnt lgkmcnt(0)" ::: "memory");  // s_sim visible

  // C: per query: softmax; out = sum an*v[g] + (sum an*t1_n)@pw2 + pb2.
  // t1_n recomputed bit-identically (same inputs/ops as phase A).
#define RL(x, l) __uint_as_float(__builtin_amdgcn_readlane(__float_as_uint(x), (l)))
#pragma unroll
  for (int qq = 0; qq < 2; qq++) {
    float px = qq ? qpb.x : qpa.x;
    float py = qq ? qpb.y : qpa.y;
    float pz = qq ? qpb.z : qpa.z;
    float mx = -3.402823466e38f;
#pragma unroll
    for (int n = 0; n < KNB; n++) mx = fmaxf(mx, s_sim[wv][qq][n]);
    float sum = 0.f;
#pragma unroll
    for (int n = 0; n < KNB; n++) sum += expf(s_sim[wv][qq][n] - mx);
    float inv = 1.f / sum;
    float o = 0.f;
    float sac = 0.f;
#pragma unroll
    for (int n = 0; n < KNB; n++) {
      float an = expf(s_sim[wv][qq][n] - mx) * inv;
      int g = s_nb[wv][qq][n];
      o += an * v[(size_t)g * 64 + lane];
      float4 np = spk4[g];
      float t1n = fmaxf(b1h + (px - np.x) * w1x + (py - np.y) * w1y +
                            (pz - np.z) * w1z, 0.f);
      sac += an * t1n;
    }
    float r = pb2[lane];
#pragma unroll 8
    for (int j = 0; j < 64; j++) r += RL(sac, j) * pw2[j * 64 + lane];
    xout[(size_t)(q0 + qq) * 64 + lane] = o + r;
  }
#undef RL
}

// ---------------------------------------------------------------------------
// K5a/K5b: parallel max-pool + head (order-invariant; sorted act OK).
// ---------------------------------------------------------------------------
__global__ __launch_bounds__(256) void k_pool(const float* __restrict__ x,
                                              float* __restrict__ pmax) {
  __shared__ float red[4][64];
  int b = blockIdx.x >> 6, blk = blockIdx.x & 63;
  int tid = threadIdx.x;
  int c = tid & 63, pg = tid >> 6;
  int p0 = blk * 128;
  float mx = -3.402823466e38f;
  for (int p = pg; p < 128; p += 4)
    mx = fmaxf(mx, x[((size_t)b * NPTS + p0 + p) * 64 + c]);
  red[pg][c] = mx;
  __syncthreads();
  if (tid < 64)
    pmax[(size_t)blockIdx.x * 64 + c] =
        fmaxf(fmaxf(red[0][c], red[1][c]), fmaxf(red[2][c], red[3][c]));
}

__global__ __launch_bounds__(256) void k_final2(const float* __restrict__ pmax,
                                                const float* __restrict__ fc1w,
                                                const float* __restrict__ fc1b,
                                                const float* __restrict__ fc3w,
                                                const float* __restrict__ fc3b,
                                                float* __restrict__ out) {
  __shared__ float red[4][64];
  __shared__ float m[64];
  __shared__ float h1[32];
  int b = blockIdx.x;
  int tid = threadIdx.x;
  int c = tid & 63, pg = tid >> 6;
  float mx = -3.402823466e38f;
  for (int blk = pg; blk < 64; blk += 4)
    mx = fmaxf(mx, pmax[(size_t)(b * 64 + blk) * 64 + c]);
  red[pg][c] = mx;
  __syncthreads();
  if (tid < 64)
    m[c] = fmaxf(fmaxf(red[0][c], red[1][c]), fmaxf(red[2][c], red[3][c]));
  __syncthreads();
  if (tid < 32) {
    float a = fc1b[tid];
#pragma unroll 8
    for (int k = 0; k < 64; k++) a += m[k] * fc1w[k * 32 + tid];
    h1[tid] = fmaxf(a, 0.f);
  }
  __syncthreads();
  if (tid < 3) {
    float a = fc3b[tid];
#pragma unroll
    for (int k = 0; k < 32; k++) a += h1[k] * fc3w[k * 3 + tid];
    out[b * 3 + tid] = a;
  }
}

// ---------------------------------------------------------------------------
// Workspace (peak ~44.8 MB):
//   idx @ 0 (1.31MB) | spk @ 1408KB (256KB; LIVE through both layers)
//   WA @ 1664KB (64KB f16 stacked A-frags) | c0 @ 1728KB (1KB)
//   pmax @ 1732KB (32KB) | cellStart @ 1764KB (33KB) | cnt+cnt2 @ 1800KB
//   WFB @ 1864KB (40KB) | v @ 2MB (4.2MB)
//   xb1 @ 6.5MB (4.2MB; layer ping-pong buffer — old kh region)
//   qh @ 23.5MB (16.8MB) | act @ 40.5MB (4.2MB)
// ---------------------------------------------------------------------------
extern "C" void kernel_launch(void* const* d_in, const int* in_sizes, int n_in,
                              void* d_out, int out_size, void* d_ws,
                              size_t ws_size, hipStream_t stream) {
  const float* pts    = (const float*)d_in[0];
  const float* conv_w = (const float*)d_in[1];
  const float* conv_b = (const float*)d_in[2];
  const float* fc1w = (const float*)d_in[21];
  const float* fc1b = (const float*)d_in[22];
  const float* fc3w = (const float*)d_in[23];
  const float* fc3b = (const float*)d_in[24];
  float* outp = (float*)d_out;

  char* ws = (char*)d_ws;
  int*      idx   = (int*)    (ws);
  float4*   spk   = (float4*) (ws + (size_t)1408 * 1024);
  _Float16* WA    = (_Float16*)(ws + (size_t)1664 * 1024);  // 64KB
  float*    c0    = (float*)  (ws + (size_t)1728 * 1024);
  float*    pmax  = (float*)  (ws + (size_t)1732 * 1024);
  int*      cellS = (int*)    (ws + (size_t)1764 * 1024);
  int*      cnt   = (int*)    (ws + (size_t)1800 * 1024);   // cnt + cnt2
  int*      cnt2  = cnt + BATCH * NCELL;
  _Float16* WFB   = (_Float16*)(ws + (size_t)1864 * 1024);  // 40KB
  float*    v     = (float*)  (ws + (size_t)2 * 1048576);
  float*    xb1   = (float*)  (ws + (size_t)6656 * 1024);   // 4.2MB ping-pong
  float*    qh    = (float*)  (ws + (size_t)24064 * 1024);
  float*    act   = (float*)  (ws + (size_t)41472 * 1024);

  k_zero<<<(2 * BATCH * NCELL + 255) / 256, 256, 0, stream>>>(cnt);
  k_hist<<<(TOTAL + 255) / 256, 256, 0, stream>>>(pts, cnt);
  k_scan<<<BATCH, 256, 0, stream>>>(cnt, cellS);
  k_scatter<<<(TOTAL + 255) / 256, 256, 0, stream>>>(pts, cnt2, cellS, spk);
  k_conv<<<(TOTAL * 64 + 255) / 256, 256, 0, stream>>>(spk, conv_w, conv_b, act);
  k_knn<<<TOTAL / 4, 256, 0, stream>>>(spk, cellS, idx);

  for (int layer = 0; layer < 2; layer++) {
    int base = 3 + layer * 9;
    const float* qkvw = (const float*)d_in[base + 0];
    const float* pw1  = (const float*)d_in[base + 1];
    const float* pb1  = (const float*)d_in[base + 2];
    const float* pw2  = (const float*)d_in[base + 3];
    const float* pb2  = (const float*)d_in[base + 4];
    const float* aw1  = (const float*)d_in[base + 5];
    const float* ab1  = (const float*)d_in[base + 6];
    const float* aw2  = (const float*)d_in[base + 7];
    const float* ab2  = (const float*)d_in[base + 8];
    const float* xi = (layer == 0) ? act : xb1;   // layer input
    float*       xo = (layer == 0) ? xb1 : act;   // layer output (ping-pong)
    k_wf<<<209, 256, 0, stream>>>(pw2, pb2, aw1, qkvw, WA, c0, WFB);
    k_pre2<<<TOTAL / 64, 256, 0, stream>>>(xi, (const f16x4*)WFB, c0, ab1,
                                           v, qh);
    k_attn<<<TOTAL / 8, 256, 0, stream>>>(
        spk, v, idx, xi, qh, pw1, pb1, pw2, pb2, WA, aw2, ab2, xo);
  }
  k_pool<<<BATCH * 64, 256, 0, stream>>>(act, pmax);
  k_final2<<<BATCH, 256, 0, stream>>>(pmax, fc1w, fc1b, fc3w, fc3b, outp);
}

// Round 11
// 444.478 us; speedup vs baseline: 1.6549x; 1.0096x over previous
//
#include <hip/hip_runtime.h>
#include <cstdint>
#include <cstddef>

#define KNB 20
#define NPTS 8192
#define BATCH 2
#define TOTAL (BATCH * NPTS)
#define NCELL 4096               // 16^3 grid per batch
#define SENT 0x7F800000FFFFFFFFULL  // d2=+inf, low=~0 (u64-max real key bound)
#define CAP 1024                 // per-wave candidate buffer (ints)

typedef _Float16 f16x4 __attribute__((ext_vector_type(4)));
typedef float f32x4 __attribute__((ext_vector_type(4)));

// ---------------------------------------------------------------------------
// Grid build (per batch, 16^3 cells, counting sort). All tiny (~25 µs).
// ---------------------------------------------------------------------------
__global__ __launch_bounds__(256) void k_zero(int* __restrict__ cnt) {
  int g = blockIdx.x * 256 + threadIdx.x;
  if (g < 2 * BATCH * NCELL) cnt[g] = 0;   // cnt + cnt2, contiguous
}

__global__ __launch_bounds__(256) void k_hist(const float* __restrict__ pts,
                                              int* __restrict__ cnt) {
  int p = blockIdx.x * 256 + threadIdx.x;
  if (p >= TOTAL) return;
  int b = p >> 13;
  int cx = min(15, (int)(pts[p * 3 + 0] * 16.f));
  int cy = min(15, (int)(pts[p * 3 + 1] * 16.f));
  int cz = min(15, (int)(pts[p * 3 + 2] * 16.f));
  atomicAdd(&cnt[b * NCELL + (cz * 16 + cy) * 16 + cx], 1);
}

__global__ __launch_bounds__(256) void k_scan(const int* __restrict__ cnt,
                                              int* __restrict__ cellStart) {
  __shared__ int ls[256];
  int b = blockIdx.x, t = threadIdx.x;
  const int* c = cnt + b * NCELL;
  int* cs = cellStart + b * (NCELL + 1);
  int base = t * 16;
  int s = 0;
#pragma unroll
  for (int i = 0; i < 16; i++) s += c[base + i];
  ls[t] = s;
  __syncthreads();
  for (int off = 1; off < 256; off <<= 1) {
    int v = (t >= off) ? ls[t - off] : 0;
    __syncthreads();
    ls[t] += v;
    __syncthreads();
  }
  int run = ls[t] - s;                  // exclusive prefix
#pragma unroll
  for (int i = 0; i < 16; i++) { cs[base + i] = run; run += c[base + i]; }
  if (t == 255) cs[NCELL] = run;        // sentinel = NPTS
}

// k_scatter: packed (x,y,z,orig_local_idx) per sorted slot. Coordinates are
// bit-exact copies of pts, so all downstream arithmetic is unchanged.
__global__ __launch_bounds__(256) void k_scatter(
    const float* __restrict__ pts, int* __restrict__ cnt2,
    const int* __restrict__ cellStart, float4* __restrict__ spk) {
  int p = blockIdx.x * 256 + threadIdx.x;
  if (p >= TOTAL) return;
  int b = p >> 13, pl = p & (NPTS - 1);
  float x = pts[p * 3 + 0], y = pts[p * 3 + 1], z = pts[p * 3 + 2];
  int cx = min(15, (int)(x * 16.f));
  int cy = min(15, (int)(y * 16.f));
  int cz = min(15, (int)(z * 16.f));
  int cell = (cz * 16 + cy) * 16 + cx;
  int pos = cellStart[b * (NCELL + 1) + cell] + atomicAdd(&cnt2[b * NCELL + cell], 1);
  spk[(size_t)b * NPTS + pos] = make_float4(x, y, z, __int_as_float(pl));
}

// ---------------------------------------------------------------------------
// K1: pointwise conv 3->64 + relu — SORTED space.
// ---------------------------------------------------------------------------
__global__ __launch_bounds__(256) void k_conv(const float4* __restrict__ spk,
                                              const float* __restrict__ w,
                                              const float* __restrict__ b,
                                              float* __restrict__ x0) {
  int gid = blockIdx.x * 256 + threadIdx.x;
  if (gid >= TOTAL * 64) return;
  int p = gid >> 6, c = gid & 63;
  float4 pp = spk[p];
  float acc = b[c] + pp.x * w[c] + pp.y * w[64 + c] + pp.z * w[128 + c];
  x0[gid] = fmaxf(acc, 0.f);
}

// ---------------------------------------------------------------------------
// K2: GRID KNN (R9-proven) — SORTED-space queries/outputs, INS16 grid passes.
// ---------------------------------------------------------------------------
__global__ __launch_bounds__(256) void k_knn(
    const float4* __restrict__ spk, const int* __restrict__ cellStart,
    int* __restrict__ idxbuf) {
  __shared__ int s_cand[4][CAP];       // 16 KB
  int tid = threadIdx.x;
  int wv = tid >> 6, lane = tid & 63;
  int q = blockIdx.x * 4 + wv;         // SORTED index
  int bq = q >> 13;
  const float4* bp = spk + (size_t)bq * NPTS;
  const int* cs = cellStart + bq * (NCELL + 1);
  float4 qp = bp[q & (NPTS - 1)];
  float qx = qp.x, qy = qp.y, qz = qp.z;
  int cx = min(15, (int)(qx * 16.f));
  int cy = min(15, (int)(qy * 16.f));
  int cz = min(15, (int)(qz * 16.f));

  unsigned long long key[KNB];
  float tau19 = __uint_as_float(0x7F800000u);
  int pass_ok = 0;

#define INS(KK)                                                              \
  if ((KK) < key[KNB - 1]) {                                                 \
    _Pragma("unroll")                                                        \
    for (int j = KNB - 1; j >= 0; j--) {                                     \
      bool cj = (KK) < key[j];                                               \
      bool cjm1 = (j > 0) && ((KK) < key[j - 1]);                            \
      if (cj) key[j] = cjm1 ? key[j - 1] : (KK);                             \
    }                                                                        \
  }

#define INS16(KK)                                                            \
  if ((KK) < key[15]) {                                                      \
    _Pragma("unroll")                                                        \
    for (int j = 15; j >= 0; j--) {                                          \
      bool cj = (KK) < key[j];                                               \
      bool cjm1 = (j > 0) && ((KK) < key[j - 1]);                            \
      if (cj) key[j] = cjm1 ? key[j - 1] : (KK);                             \
    }                                                                        \
  }

#define PASS(RR, WW, NRR, BOUND)                                             \
  {                                                                          \
    _Pragma("unroll")                                                        \
    for (int j = 0; j < KNB; j++) key[j] = SENT;                             \
    int sv = 0, lenv = 0;                                                    \
    if (lane < (NRR)) {                                                      \
      int dz = lane / (WW) - (RR), dy = lane % (WW) - (RR);                  \
      int z = cz + dz, y = cy + dy;                                          \
      if ((unsigned)z < 16u && (unsigned)y < 16u) {                          \
        int x0 = cx - (RR); if (x0 < 0) x0 = 0;                              \
        int x1 = cx + (RR); if (x1 > 15) x1 = 15;                            \
        int rb = (z * 16 + y) * 16;                                          \
        sv = cs[rb + x0];                                                    \
        lenv = cs[rb + x1 + 1] - sv;                                         \
      }                                                                      \
    }                                                                        \
    int pre = lenv;                                                          \
    _Pragma("unroll")                                                        \
    for (int off = 1; off < 64; off <<= 1) {                                 \
      int o = __shfl_up(pre, off);                                           \
      if (lane >= off) pre += o;                                             \
    }                                                                        \
    int T = __shfl(pre, 63);                                                 \
    int excl = pre - lenv;                                                   \
    asm volatile("s_waitcnt lgkmcnt(0)" ::: "memory"); /* WAR vs prior pass */\
    for (int k2 = 0; k2 < lenv; k2++) {                                      \
      int wpos = excl + k2;                                                  \
      if (wpos < CAP) s_cand[wv][wpos] = sv + k2;                            \
    }                                                                        \
    asm volatile("s_waitcnt lgkmcnt(0)" ::: "memory"); /* RAW: writes done */\
    int Tc = T < CAP ? T : CAP;                                              \
    for (int t = lane; t < Tc; t += 64) {                                    \
      int ci = s_cand[wv][t];                                                \
      float4 pk = bp[ci];                                                    \
      float dxv = qx - pk.x, dyv = qy - pk.y, dzv = qz - pk.z;               \
      float d2 = __fadd_rn(__fadd_rn(__fmul_rn(dxv, dxv),                    \
                                     __fmul_rn(dyv, dyv)),                   \
                           __fmul_rn(dzv, dzv));                             \
      unsigned long long kk =                                                \
          ((unsigned long long)__float_as_uint(d2) << 32) |                  \
          ((unsigned)__float_as_uint(pk.w) << 13) | (unsigned)ci;            \
      INS16(kk)                                                              \
    }                                                                        \
    float h = __uint_as_float((unsigned)(key[0] >> 32));                     \
    _Pragma("unroll")                                                        \
    for (int kk2 = 2; kk2 <= 64; kk2 <<= 1) {                                \
      _Pragma("unroll")                                                      \
      for (int j = kk2 >> 1; j > 0; j >>= 1) {                               \
        float o = __shfl_xor(h, j);                                          \
        bool up = ((lane & kk2) == 0);                                       \
        bool lower = ((lane & j) == 0);                                      \
        bool takeMin = (up == lower);                                        \
        bool lt = h < o;                                                     \
        h = (takeMin == lt) ? h : o;                                         \
      }                                                                      \
    }                                                                        \
    tau19 = __shfl(h, 19);                                                   \
    pass_ok = (T <= CAP) && (tau19 < (BOUND));                               \
  }

  float fx = fminf(qx, 1.f - qx), fy = fminf(qy, 1.f - qy),
        fz = fminf(qz, 1.f - qz);
  int nearf = (fx < 0.13f) + (fy < 0.13f) + (fz < 0.13f);

  if (nearf < 2) PASS(2, 5, 25, 0.0155f)
  if (!pass_ok)  PASS(3, 7, 49, 0.0351f)
#undef PASS

  if (!pass_ok) {
    // exact rescan of all 8192 with tau filter, from scratch (depth 20).
#pragma unroll
    for (int j = 0; j < KNB; j++) key[j] = SENT;
    for (int g = 0; g < 32; g++) {
      int i0 = g * 256 + lane * 4;
#pragma unroll
      for (int c = 0; c < 4; c++) {
        float4 pk = bp[i0 + c];
        float dxv = qx - pk.x, dyv = qy - pk.y, dzv = qz - pk.z;
        float d2 = __fadd_rn(__fadd_rn(__fmul_rn(dxv, dxv),
                                       __fmul_rn(dyv, dyv)),
                             __fmul_rn(dzv, dzv));
        if (d2 <= tau19) {
          unsigned long long kk =
              ((unsigned long long)__float_as_uint(d2) << 32) |
              ((unsigned)__float_as_uint(pk.w) << 13) | (unsigned)(i0 + c);
          INS(kk)
        }
      }
    }
  }
#undef INS
#undef INS16

  int bqoff = bq * NPTS;
  for (int step = 0; step < KNB; step++) {
    unsigned long long p = key[0];
    unsigned long long m = p;
#pragma unroll
    for (int off = 32; off >= 1; off >>= 1) {
      unsigned long long o = __shfl_xor(m, off);
      m = (o < m) ? o : m;
    }
    if (lane == 0) idxbuf[q * KNB + step] = bqoff + (int)(m & 0x1FFFULL);
    if (p == m) {
#pragma unroll
      for (int j = 0; j < KNB - 1; j++) key[j] = key[j + 1];
      key[KNB - 1] = SENT;
    }
  }
}

// ---------------------------------------------------------------------------
// K3: fused per-layer weight fold (R10-proven).
//  WA (64KB): A-frags of the STACKED operator [W2 | Wk'] (256 x K=128).
//  c0 (f32): pb2@aw1_bot.  WFB (40KB): B-frags for pre2: qh|v.
// ---------------------------------------------------------------------------
__global__ __launch_bounds__(256) void k_wf(const float* __restrict__ pw2,
                                            const float* __restrict__ pb2,
                                            const float* __restrict__ aw1,
                                            const float* __restrict__ qkvw,
                                            _Float16* __restrict__ WA,
                                            float* __restrict__ c0,
                                            _Float16* __restrict__ WFB) {
  int b = blockIdx.x;
  if (b < 65) {
    int h = b, c = threadIdx.x;
    float a = 0.f;
    if (h < 64) {
#pragma unroll 8
      for (int j = 0; j < 64; j++)
        a += pw2[h * 64 + j] * aw1[(size_t)(64 + j) * 256 + c];
      int mt = c >> 4, lo = c & 15;
      int ks = h >> 4, hi = (h >> 2) & 3, el = h & 3;
      WA[(size_t)(((mt * 8 + ks) * 64) + hi * 16 + lo) * 4 + el] = (_Float16)a;
    } else {
#pragma unroll 8
      for (int j = 0; j < 64; j++)
        a += pb2[j] * aw1[(size_t)(64 + j) * 256 + c];
      c0[c] = a;
    }
  } else {
    int id = (b - 65) * 256 + threadIdx.x;   // 144 blocks x 256 = 36864
    int h = id & 63, c = id >> 6;
    int ks = h >> 4, hi = (h >> 2) & 3, e = h & 3;
    float a = 0.f;
    if (c < 256) {
      // Wk' = Wk@aw1_top -> A-frag upper-K half (ks 4..7)
#pragma unroll 8
      for (int j = 0; j < 64; j++)
        a += qkvw[h * 192 + 64 + j] * aw1[(size_t)j * 256 + c];
      int mt = c >> 4, lo = c & 15;
      WA[(size_t)(((mt * 8 + 4 + ks) * 64) + hi * 16 + lo) * 4 + e] = (_Float16)a;
    } else if (c < 512) {
      int cc = c - 256;
#pragma unroll 8
      for (int j = 0; j < 64; j++)
        a += qkvw[h * 192 + j] * aw1[(size_t)j * 256 + cc];
      int nt = cc >> 4, lo = cc & 15;     // qh tiles 0..15
      WFB[(size_t)(((nt * 4 + ks) * 64) + hi * 16 + lo) * 4 + e] = (_Float16)a;
    } else {
      int cc = c - 512;
      a = qkvw[h * 192 + 128 + cc];
      int nt = 16 + (cc >> 4), lo = cc & 15;  // v tiles 16..19
      WFB[(size_t)(((nt * 4 + ks) * 64) + hi * 16 + lo) * 4 + e] = (_Float16)a;
    }
  }
}

// ---------------------------------------------------------------------------
// K3b: k_pre2 — MFMA GEMM producing qh|v only (R10-proven).
// ---------------------------------------------------------------------------
__global__ __launch_bounds__(256) void k_pre2(const float* __restrict__ x,
                                              const f16x4* __restrict__ WFB,
                                              const float* __restrict__ c0,
                                              const float* __restrict__ ab1,
                                              float* __restrict__ v,
                                              float* __restrict__ qh) {
  int tid = threadIdx.x;
  int wv = tid >> 6, lane = tid & 63;
  int mt = blockIdx.x * 4 + wv;
  int m0 = mt * 16;
  int lo = lane & 15, hi = lane >> 4;

  f16x4 af[4];
#pragma unroll
  for (int ks = 0; ks < 4; ks++) {
    float4 xv = *(const float4*)&x[(size_t)(m0 + lo) * 64 + ks * 16 + hi * 4];
    f16x4 a;
    a[0] = (_Float16)xv.x; a[1] = (_Float16)xv.y;
    a[2] = (_Float16)xv.z; a[3] = (_Float16)xv.w;
    af[ks] = a;
  }

#pragma unroll 4
  for (int nt = 0; nt < 20; nt++) {
    f32x4 acc = {0.f, 0.f, 0.f, 0.f};
#pragma unroll
    for (int ks = 0; ks < 4; ks++)
      acc = __builtin_amdgcn_mfma_f32_16x16x16f16(af[ks],
                                                  WFB[(nt * 4 + ks) * 64 + lane],
                                                  acc, 0, 0, 0);
    if (nt < 16) {
      int col = nt * 16 + lo;
      float bv = c0[col] + ab1[col];
#pragma unroll
      for (int r = 0; r < 4; r++)
        qh[(size_t)(m0 + hi * 4 + r) * 256 + col] = acc[r] + bv;
    } else {
      int col = (nt - 16) * 16 + lo;
#pragma unroll
      for (int r = 0; r < 4; r++)
        v[(size_t)(m0 + hi * 4 + r) * 64 + col] = acc[r];
    }
  }
}

// ---------------------------------------------------------------------------
// K4: attention — R10 stacked-MFMA structure + R11 phase-C critical-path
//  shortening: (1) softmax max/sum via 6-step shfl trees (lane n owns sim_n)
//  instead of 20-serial chains; (2) exp computed ONCE per n, cached in
//  s_sim; (3) o/sac accumulate raw e_n (divide factored out of the loop);
//  (4) RL GEMV split into two accumulators. All reassociations are
//  f32-rounding-level only.
// ---------------------------------------------------------------------------
__global__ __launch_bounds__(256, 4) void k_attn(
    const float4* __restrict__ spk4, const float* __restrict__ v,
    const int* __restrict__ idxbuf, const float* __restrict__ xin,
    const float* __restrict__ qh,
    const float* __restrict__ pw1, const float* __restrict__ pb1,
    const float* __restrict__ pw2, const float* __restrict__ pb2,
    const _Float16* __restrict__ WA,
    const float* __restrict__ aw2, const float* __restrict__ ab2,
    float* __restrict__ xout) {
  __shared__ __align__(16) _Float16 s_t1x[4][2560];  // 20 KB: 20 rows x K=128
  __shared__ float s_sim[4][2][KNB];
  __shared__ int   s_nb[4][2][24];

  int tid = threadIdx.x;
  int wv = tid >> 6, lane = tid & 63;
  int q0 = blockIdx.x * 8 + wv * 2;          // this wave: queries q0, q0+1
  int lo = lane & 15, hi = lane >> 4;

  if (lane < KNB) {
    s_nb[wv][0][lane] = idxbuf[q0 * KNB + lane];
    s_nb[wv][1][lane] = idxbuf[(q0 + 1) * KNB + lane];
  }
  float4 qpa = spk4[q0];
  float4 qpb = spk4[q0 + 1];
  asm volatile("s_waitcnt lgkmcnt(0)" ::: "memory");  // s_nb visible to wave

  float w1x = pw1[lane], w1y = pw1[64 + lane], w1z = pw1[128 + lane];
  float b1h = pb1[lane];

  // A: per query: stage [t1(k=0..63); -x_g(k=64..127)] f16 swizzled -> frags.
  f16x4 bfab[2][8];
  f16x4 bf1[8];
#pragma unroll
  for (int ks = 0; ks < 8; ks++) {
    f16x4 z = {(_Float16)0.f, (_Float16)0.f, (_Float16)0.f, (_Float16)0.f};
    bf1[ks] = z;
  }
#pragma unroll
  for (int qq = 0; qq < 2; qq++) {
    float px = qq ? qpb.x : qpa.x;
    float py = qq ? qpb.y : qpa.y;
    float pz = qq ? qpb.z : qpa.z;
#pragma unroll
    for (int n = 0; n < KNB; n++) {
      int g = s_nb[wv][qq][n];
      float4 np = spk4[g];
      float t1n = fmaxf(b1h + (px - np.x) * w1x + (py - np.y) * w1y +
                            (pz - np.z) * w1z, 0.f);
      int sw = (n & 7) << 3;
      s_t1x[wv][n * 128 + (lane ^ sw)] = (_Float16)t1n;
      float xg = xin[(size_t)g * 64 + lane];
      s_t1x[wv][n * 128 + ((64 + lane) ^ sw)] = (_Float16)(-xg);
    }
    asm volatile("s_waitcnt lgkmcnt(0)" ::: "memory");  // writes visible
    // frags: lane(lo,hi) -> B[k=ks*16+4*hi..+3][col]; col=lo for main tile.
#pragma unroll
    for (int ks = 0; ks < 8; ks++) {
      int k0 = ks * 16 + hi * 4;
      bfab[qq][ks] =
          *(const f16x4*)&s_t1x[wv][lo * 128 + (k0 ^ ((lo & 7) << 3))];
      if (qq == 0) {
        if (lo < 4) {
          int n = 16 + lo;
          bf1[ks] = *(const f16x4*)&s_t1x[wv][n * 128 + (k0 ^ ((n & 7) << 3))];
        }
      } else {
        if (lo >= 4 && lo < 8) {
          int n = 12 + lo;        // 16 + (lo-4)
          bf1[ks] = *(const f16x4*)&s_t1x[wv][n * 128 + (k0 ^ ((n & 7) << 3))];
        }
      }
    }
    asm volatile("s_waitcnt lgkmcnt(0)" ::: "memory");  // reads done (WAR)
  }

  const f16x4* WA4 = (const f16x4*)WA;
  const float* qhra = &qh[(size_t)q0 * 256];
  const float* qhrb = &qh[(size_t)(q0 + 1) * 256];
  float sim0a = 0.f, sim0b = 0.f, sim1 = 0.f;

#pragma unroll 2
  for (int mt = 0; mt < 16; mt++) {
    f32x4 a0a = {0.f, 0.f, 0.f, 0.f};
    f32x4 a0b = {0.f, 0.f, 0.f, 0.f};
    f32x4 a1  = {0.f, 0.f, 0.f, 0.f};
#pragma unroll
    for (int ks = 0; ks < 8; ks++) {
      f16x4 af = WA4[(mt * 8 + ks) * 64 + lane];
      a0a = __builtin_amdgcn_mfma_f32_16x16x16f16(af, bfab[0][ks], a0a, 0, 0, 0);
      a0b = __builtin_amdgcn_mfma_f32_16x16x16f16(af, bfab[1][ks], a0b, 0, 0, 0);
      a1  = __builtin_amdgcn_mfma_f32_16x16x16f16(af, bf1[ks],     a1,  0, 0, 0);
    }
    int cb = mt * 16 + hi * 4;
    float4 w24 = *(const float4*)&aw2[cb];
    float4 qa4 = *(const float4*)&qhra[cb];
    float4 qb4 = *(const float4*)&qhrb[cb];
    sim0a += fmaxf(a0a[0] + qa4.x, 0.f) * w24.x +
             fmaxf(a0a[1] + qa4.y, 0.f) * w24.y +
             fmaxf(a0a[2] + qa4.z, 0.f) * w24.z +
             fmaxf(a0a[3] + qa4.w, 0.f) * w24.w;
    sim0b += fmaxf(a0b[0] + qb4.x, 0.f) * w24.x +
             fmaxf(a0b[1] + qb4.y, 0.f) * w24.y +
             fmaxf(a0b[2] + qb4.z, 0.f) * w24.z +
             fmaxf(a0b[3] + qb4.w, 0.f) * w24.w;
    float4 q14;                       // register select: q0 rows on lo<4
    q14.x = (lo < 4) ? qa4.x : qb4.x; q14.y = (lo < 4) ? qa4.y : qb4.y;
    q14.z = (lo < 4) ? qa4.z : qb4.z; q14.w = (lo < 4) ? qa4.w : qb4.w;
    sim1  += fmaxf(a1[0] + q14.x, 0.f) * w24.x +
             fmaxf(a1[1] + q14.y, 0.f) * w24.y +
             fmaxf(a1[2] + q14.z, 0.f) * w24.z +
             fmaxf(a1[3] + q14.w, 0.f) * w24.w;
  }
  // reduce over hi (XOR 16/32 keeps lo fixed; garbage lanes isolated).
  sim0a += __shfl_xor(sim0a, 16); sim0a += __shfl_xor(sim0a, 32);
  sim0b += __shfl_xor(sim0b, 16); sim0b += __shfl_xor(sim0b, 32);
  sim1  += __shfl_xor(sim1, 16);  sim1  += __shfl_xor(sim1, 32);
  float ab2v = ab2[0];
  if (lane < 16) s_sim[wv][0][lane] = sim0a + ab2v;
  if (lane < 16) s_sim[wv][1][lane] = sim0b + ab2v;
  if (lane < 4)       s_sim[wv][0][16 + lane] = sim1 + ab2v;       // q0 ovf
  else if (lane < 8)  s_sim[wv][1][12 + lane] = sim1 + ab2v;       // q1 ovf
  asm volatile("s_waitcnt lgkmcnt(0)" ::: "memory");  // s_sim visible

  // C: per query: wave-parallel softmax (shfl trees, exp cached in LDS);
  // out = inv*(sum e_n*v[g]) + (inv*(sum e_n*t1_n))@pw2 + pb2.
  // t1_n recomputed bit-identically (same inputs/ops as phase A).
#define RL(x, l) __uint_as_float(__builtin_amdgcn_readlane(__float_as_uint(x), (l)))
#pragma unroll
  for (int qq = 0; qq < 2; qq++) {
    float px = qq ? qpb.x : qpa.x;
    float py = qq ? qpb.y : qpa.y;
    float pz = qq ? qpb.z : qpa.z;
    // lane n<20 owns sim_n; max/sum via 6-step shfl trees.
    float sv_ = (lane < KNB) ? s_sim[wv][qq][lane] : -3.402823466e38f;
    float mxv = sv_;
#pragma unroll
    for (int off = 32; off >= 1; off >>= 1)
      mxv = fmaxf(mxv, __shfl_xor(mxv, off));
    float e_ = (lane < KNB) ? expf(sv_ - mxv) : 0.f;
    if (lane < KNB) s_sim[wv][qq][lane] = e_;   // cache exp once
    float sumv = e_;
#pragma unroll
    for (int off = 32; off >= 1; off >>= 1) sumv += __shfl_xor(sumv, off);
    float inv = 1.f / sumv;
    asm volatile("s_waitcnt lgkmcnt(0)" ::: "memory");  // e_ writes visible
    float o = 0.f;
    float sac = 0.f;
#pragma unroll
    for (int n = 0; n < KNB; n++) {
      float en = s_sim[wv][qq][n];              // broadcast LDS read
      int g = s_nb[wv][qq][n];
      o += en * v[(size_t)g * 64 + lane];
      float4 np = spk4[g];
      float t1n = fmaxf(b1h + (px - np.x) * w1x + (py - np.y) * w1y +
                            (pz - np.z) * w1z, 0.f);
      sac += en * t1n;
    }
    o *= inv;
    sac *= inv;
    float r = pb2[lane];
    float r1 = 0.f;
#pragma unroll 4
    for (int j = 0; j < 64; j += 2) {
      r  += RL(sac, j)     * pw2[j * 64 + lane];
      r1 += RL(sac, j + 1) * pw2[(j + 1) * 64 + lane];
    }
    xout[(size_t)(q0 + qq) * 64 + lane] = o + r + r1;
  }
#undef RL
}

// ---------------------------------------------------------------------------
// K5a/K5b: parallel max-pool + head (order-invariant; sorted act OK).
// ---------------------------------------------------------------------------
__global__ __launch_bounds__(256) void k_pool(const float* __restrict__ x,
                                              float* __restrict__ pmax) {
  __shared__ float red[4][64];
  int b = blockIdx.x >> 6, blk = blockIdx.x & 63;
  int tid = threadIdx.x;
  int c = tid & 63, pg = tid >> 6;
  int p0 = blk * 128;
  float mx = -3.402823466e38f;
  for (int p = pg; p < 128; p += 4)
    mx = fmaxf(mx, x[((size_t)b * NPTS + p0 + p) * 64 + c]);
  red[pg][c] = mx;
  __syncthreads();
  if (tid < 64)
    pmax[(size_t)blockIdx.x * 64 + c] =
        fmaxf(fmaxf(red[0][c], red[1][c]), fmaxf(red[2][c], red[3][c]));
}

__global__ __launch_bounds__(256) void k_final2(const float* __restrict__ pmax,
                                                const float* __restrict__ fc1w,
                                                const float* __restrict__ fc1b,
                                                const float* __restrict__ fc3w,
                                                const float* __restrict__ fc3b,
                                                float* __restrict__ out) {
  __shared__ float red[4][64];
  __shared__ float m[64];
  __shared__ float h1[32];
  int b = blockIdx.x;
  int tid = threadIdx.x;
  int c = tid & 63, pg = tid >> 6;
  float mx = -3.402823466e38f;
  for (int blk = pg; blk < 64; blk += 4)
    mx = fmaxf(mx, pmax[(size_t)(b * 64 + blk) * 64 + c]);
  red[pg][c] = mx;
  __syncthreads();
  if (tid < 64)
    m[c] = fmaxf(fmaxf(red[0][c], red[1][c]), fmaxf(red[2][c], red[3][c]));
  __syncthreads();
  if (tid < 32) {
    float a = fc1b[tid];
#pragma unroll 8
    for (int k = 0; k < 64; k++) a += m[k] * fc1w[k * 32 + tid];
    h1[tid] = fmaxf(a, 0.f);
  }
  __syncthreads();
  if (tid < 3) {
    float a = fc3b[tid];
#pragma unroll
    for (int k = 0; k < 32; k++) a += h1[k] * fc3w[k * 3 + tid];
    out[b * 3 + tid] = a;
  }
}

// ---------------------------------------------------------------------------
// Workspace (peak ~44.8 MB):
//   idx @ 0 (1.31MB) | spk @ 1408KB (256KB; LIVE through both layers)
//   WA @ 1664KB (64KB f16 stacked A-frags) | c0 @ 1728KB (1KB)
//   pmax @ 1732KB (32KB) | cellStart @ 1764KB (33KB) | cnt+cnt2 @ 1800KB
//   WFB @ 1864KB (40KB) | v @ 2MB (4.2MB)
//   xb1 @ 6.5MB (4.2MB; layer ping-pong buffer)
//   qh @ 23.5MB (16.8MB) | act @ 40.5MB (4.2MB)
// ---------------------------------------------------------------------------
extern "C" void kernel_launch(void* const* d_in, const int* in_sizes, int n_in,
                              void* d_out, int out_size, void* d_ws,
                              size_t ws_size, hipStream_t stream) {
  const float* pts    = (const float*)d_in[0];
  const float* conv_w = (const float*)d_in[1];
  const float* conv_b = (const float*)d_in[2];
  const float* fc1w = (const float*)d_in[21];
  const float* fc1b = (const float*)d_in[22];
  const float* fc3w = (const float*)d_in[23];
  const float* fc3b = (const float*)d_in[24];
  float* outp = (float*)d_out;

  char* ws = (char*)d_ws;
  int*      idx   = (int*)    (ws);
  float4*   spk   = (float4*) (ws + (size_t)1408 * 1024);
  _Float16* WA    = (_Float16*)(ws + (size_t)1664 * 1024);  // 64KB
  float*    c0    = (float*)  (ws + (size_t)1728 * 1024);
  float*    pmax  = (float*)  (ws + (size_t)1732 * 1024);
  int*      cellS = (int*)    (ws + (size_t)1764 * 1024);
  int*      cnt   = (int*)    (ws + (size_t)1800 * 1024);   // cnt + cnt2
  int*      cnt2  = cnt + BATCH * NCELL;
  _Float16* WFB   = (_Float16*)(ws + (size_t)1864 * 1024);  // 40KB
  float*    v     = (float*)  (ws + (size_t)2 * 1048576);
  float*    xb1   = (float*)  (ws + (size_t)6656 * 1024);   // 4.2MB ping-pong
  float*    qh    = (float*)  (ws + (size_t)24064 * 1024);
  float*    act   = (float*)  (ws + (size_t)41472 * 1024);

  k_zero<<<(2 * BATCH * NCELL + 255) / 256, 256, 0, stream>>>(cnt);
  k_hist<<<(TOTAL + 255) / 256, 256, 0, stream>>>(pts, cnt);
  k_scan<<<BATCH, 256, 0, stream>>>(cnt, cellS);
  k_scatter<<<(TOTAL + 255) / 256, 256, 0, stream>>>(pts, cnt2, cellS, spk);
  k_conv<<<(TOTAL * 64 + 255) / 256, 256, 0, stream>>>(spk, conv_w, conv_b, act);
  k_knn<<<TOTAL / 4, 256, 0, stream>>>(spk, cellS, idx);

  for (int layer = 0; layer < 2; layer++) {
    int base = 3 + layer * 9;
    const float* qkvw = (const float*)d_in[base + 0];
    const float* pw1  = (const float*)d_in[base + 1];
    const float* pb1  = (const float*)d_in[base + 2];
    const float* pw2  = (const float*)d_in[base + 3];
    const float* pb2  = (const float*)d_in[base + 4];
    const float* aw1  = (const float*)d_in[base + 5];
    const float* ab1  = (const float*)d_in[base + 6];
    const float* aw2  = (const float*)d_in[base + 7];
    const float* ab2  = (const float*)d_in[base + 8];
    const float* xi = (layer == 0) ? act : xb1;   // layer input
    float*       xo = (layer == 0) ? xb1 : act;   // layer output (ping-pong)
    k_wf<<<209, 256, 0, stream>>>(pw2, pb2, aw1, qkvw, WA, c0, WFB);
    k_pre2<<<TOTAL / 64, 256, 0, stream>>>(xi, (const f16x4*)WFB, c0, ab1,
                                           v, qh);
    k_attn<<<TOTAL / 8, 256, 0, stream>>>(
        spk, v, idx, xi, qh, pw1, pb1, pw2, pb2, WA, aw2, ab2, xo);
  }
  k_pool<<<BATCH * 64, 256, 0, stream>>>(act, pmax);
  k_final2<<<BATCH, 256, 0, stream>>>(pmax, fc1w, fc1b, fc3w, fc3b, outp);
}

// Round 12
// 442.168 us; speedup vs baseline: 1.6635x; 1.0052x over previous
//
#include <hip/hip_runtime.h>
#include <cstdint>
#include <cstddef>

#define KNB 20
#define NPTS 8192
#define BATCH 2
#define TOTAL (BATCH * NPTS)
#define NCELL 4096               // 16^3 grid per batch
#define SENT 0x7F800000FFFFFFFFULL  // d2=+inf, low=~0 (u64-max real key bound)
#define CAP 1024                 // per-wave candidate buffer (ints)

typedef _Float16 f16x4 __attribute__((ext_vector_type(4)));
typedef float f32x4 __attribute__((ext_vector_type(4)));

// ---------------------------------------------------------------------------
// Grid build (per batch, 16^3 cells, counting sort). All tiny (~25 µs).
// ---------------------------------------------------------------------------
__global__ __launch_bounds__(256) void k_zero(int* __restrict__ cnt) {
  int g = blockIdx.x * 256 + threadIdx.x;
  if (g < 2 * BATCH * NCELL) cnt[g] = 0;   // cnt + cnt2, contiguous
}

__global__ __launch_bounds__(256) void k_hist(const float* __restrict__ pts,
                                              int* __restrict__ cnt) {
  int p = blockIdx.x * 256 + threadIdx.x;
  if (p >= TOTAL) return;
  int b = p >> 13;
  int cx = min(15, (int)(pts[p * 3 + 0] * 16.f));
  int cy = min(15, (int)(pts[p * 3 + 1] * 16.f));
  int cz = min(15, (int)(pts[p * 3 + 2] * 16.f));
  atomicAdd(&cnt[b * NCELL + (cz * 16 + cy) * 16 + cx], 1);
}

__global__ __launch_bounds__(256) void k_scan(const int* __restrict__ cnt,
                                              int* __restrict__ cellStart) {
  __shared__ int ls[256];
  int b = blockIdx.x, t = threadIdx.x;
  const int* c = cnt + b * NCELL;
  int* cs = cellStart + b * (NCELL + 1);
  int base = t * 16;
  int s = 0;
#pragma unroll
  for (int i = 0; i < 16; i++) s += c[base + i];
  ls[t] = s;
  __syncthreads();
  for (int off = 1; off < 256; off <<= 1) {
    int v = (t >= off) ? ls[t - off] : 0;
    __syncthreads();
    ls[t] += v;
    __syncthreads();
  }
  int run = ls[t] - s;                  // exclusive prefix
#pragma unroll
  for (int i = 0; i < 16; i++) { cs[base + i] = run; run += c[base + i]; }
  if (t == 255) cs[NCELL] = run;        // sentinel = NPTS
}

// k_scatter: packed (x,y,z,orig_local_idx) per sorted slot. Coordinates are
// bit-exact copies of pts, so all downstream arithmetic is unchanged.
__global__ __launch_bounds__(256) void k_scatter(
    const float* __restrict__ pts, int* __restrict__ cnt2,
    const int* __restrict__ cellStart, float4* __restrict__ spk) {
  int p = blockIdx.x * 256 + threadIdx.x;
  if (p >= TOTAL) return;
  int b = p >> 13, pl = p & (NPTS - 1);
  float x = pts[p * 3 + 0], y = pts[p * 3 + 1], z = pts[p * 3 + 2];
  int cx = min(15, (int)(x * 16.f));
  int cy = min(15, (int)(y * 16.f));
  int cz = min(15, (int)(z * 16.f));
  int cell = (cz * 16 + cy) * 16 + cx;
  int pos = cellStart[b * (NCELL + 1) + cell] + atomicAdd(&cnt2[b * NCELL + cell], 1);
  spk[(size_t)b * NPTS + pos] = make_float4(x, y, z, __int_as_float(pl));
}

// ---------------------------------------------------------------------------
// K1: pointwise conv 3->64 + relu — SORTED space.
// ---------------------------------------------------------------------------
__global__ __launch_bounds__(256) void k_conv(const float4* __restrict__ spk,
                                              const float* __restrict__ w,
                                              const float* __restrict__ b,
                                              float* __restrict__ x0) {
  int gid = blockIdx.x * 256 + threadIdx.x;
  if (gid >= TOTAL * 64) return;
  int p = gid >> 6, c = gid & 63;
  float4 pp = spk[p];
  float acc = b[c] + pp.x * w[c] + pp.y * w[64 + c] + pp.z * w[128 + c];
  x0[gid] = fmaxf(acc, 0.f);
}

// ---------------------------------------------------------------------------
// K2: GRID KNN — SORTED-space queries/outputs.
//  R12: R=2 pass uses a DEPTH-8 per-lane list, exact because balanced
//  round-robin gives each lane <= ceil(T/64) candidates and pass validity
//  now requires T <= 512 (so <= 8/lane -> list is COMPLETE). Lane minima
//  (hence tau19) are depth-independent. T > 512 skips the R2 gather and
//  escalates to R=3/depth-16 (keys reset there; fallback uses R3's tau19).
// ---------------------------------------------------------------------------
__global__ __launch_bounds__(256) void k_knn(
    const float4* __restrict__ spk, const int* __restrict__ cellStart,
    int* __restrict__ idxbuf) {
  __shared__ int s_cand[4][CAP];       // 16 KB
  int tid = threadIdx.x;
  int wv = tid >> 6, lane = tid & 63;
  int q = blockIdx.x * 4 + wv;         // SORTED index
  int bq = q >> 13;
  const float4* bp = spk + (size_t)bq * NPTS;
  const int* cs = cellStart + bq * (NCELL + 1);
  float4 qp = bp[q & (NPTS - 1)];
  float qx = qp.x, qy = qp.y, qz = qp.z;
  int cx = min(15, (int)(qx * 16.f));
  int cy = min(15, (int)(qy * 16.f));
  int cz = min(15, (int)(qz * 16.f));

  unsigned long long key[KNB];
  float tau19 = __uint_as_float(0x7F800000u);
  int pass_ok = 0;

#define INS(KK)                                                              \
  if ((KK) < key[KNB - 1]) {                                                 \
    _Pragma("unroll")                                                        \
    for (int j = KNB - 1; j >= 0; j--) {                                     \
      bool cj = (KK) < key[j];                                               \
      bool cjm1 = (j > 0) && ((KK) < key[j - 1]);                            \
      if (cj) key[j] = cjm1 ? key[j - 1] : (KK);                             \
    }                                                                        \
  }

#define INS8(KK)                                                             \
  if ((KK) < key[7]) {                                                       \
    _Pragma("unroll")                                                        \
    for (int j = 7; j >= 0; j--) {                                           \
      bool cj = (KK) < key[j];                                               \
      bool cjm1 = (j > 0) && ((KK) < key[j - 1]);                            \
      if (cj) key[j] = cjm1 ? key[j - 1] : (KK);                             \
    }                                                                        \
  }

#define INS16(KK)                                                            \
  if ((KK) < key[15]) {                                                      \
    _Pragma("unroll")                                                        \
    for (int j = 15; j >= 0; j--) {                                          \
      bool cj = (KK) < key[j];                                               \
      bool cjm1 = (j > 0) && ((KK) < key[j - 1]);                            \
      if (cj) key[j] = cjm1 ? key[j - 1] : (KK);                             \
    }                                                                        \
  }

// TLIM: max candidate count for which this pass's per-lane list depth is
// complete. FALLT: gather extent when T > TLIM (0 = skip wasted gather).
#define PASS(RR, WW, NRR, BOUND, TLIM, FALLT, INSX)                          \
  {                                                                          \
    _Pragma("unroll")                                                        \
    for (int j = 0; j < KNB; j++) key[j] = SENT;                             \
    int sv = 0, lenv = 0;                                                    \
    if (lane < (NRR)) {                                                      \
      int dz = lane / (WW) - (RR), dy = lane % (WW) - (RR);                  \
      int z = cz + dz, y = cy + dy;                                          \
      if ((unsigned)z < 16u && (unsigned)y < 16u) {                          \
        int x0 = cx - (RR); if (x0 < 0) x0 = 0;                              \
        int x1 = cx + (RR); if (x1 > 15) x1 = 15;                            \
        int rb = (z * 16 + y) * 16;                                          \
        sv = cs[rb + x0];                                                    \
        lenv = cs[rb + x1 + 1] - sv;                                         \
      }                                                                      \
    }                                                                        \
    int pre = lenv;                                                          \
    _Pragma("unroll")                                                        \
    for (int off = 1; off < 64; off <<= 1) {                                 \
      int o = __shfl_up(pre, off);                                           \
      if (lane >= off) pre += o;                                             \
    }                                                                        \
    int T = __shfl(pre, 63);                                                 \
    int excl = pre - lenv;                                                   \
    asm volatile("s_waitcnt lgkmcnt(0)" ::: "memory"); /* WAR vs prior pass */\
    for (int k2 = 0; k2 < lenv; k2++) {                                      \
      int wpos = excl + k2;                                                  \
      if (wpos < CAP) s_cand[wv][wpos] = sv + k2;                            \
    }                                                                        \
    asm volatile("s_waitcnt lgkmcnt(0)" ::: "memory"); /* RAW: writes done */\
    int Tc = (T <= (TLIM)) ? T : (FALLT);                                    \
    for (int t = lane; t < Tc; t += 64) {                                    \
      int ci = s_cand[wv][t];                                                \
      float4 pk = bp[ci];                                                    \
      float dxv = qx - pk.x, dyv = qy - pk.y, dzv = qz - pk.z;               \
      float d2 = __fadd_rn(__fadd_rn(__fmul_rn(dxv, dxv),                    \
                                     __fmul_rn(dyv, dyv)),                   \
                           __fmul_rn(dzv, dzv));                             \
      unsigned long long kk =                                                \
          ((unsigned long long)__float_as_uint(d2) << 32) |                  \
          ((unsigned)__float_as_uint(pk.w) << 13) | (unsigned)ci;            \
      INSX(kk)                                                               \
    }                                                                        \
    float h = __uint_as_float((unsigned)(key[0] >> 32));                     \
    _Pragma("unroll")                                                        \
    for (int kk2 = 2; kk2 <= 64; kk2 <<= 1) {                                \
      _Pragma("unroll")                                                      \
      for (int j = kk2 >> 1; j > 0; j >>= 1) {                               \
        float o = __shfl_xor(h, j);                                          \
        bool up = ((lane & kk2) == 0);                                       \
        bool lower = ((lane & j) == 0);                                      \
        bool takeMin = (up == lower);                                        \
        bool lt = h < o;                                                     \
        h = (takeMin == lt) ? h : o;                                         \
      }                                                                      \
    }                                                                        \
    tau19 = __shfl(h, 19);                                                   \
    pass_ok = (T <= (TLIM)) && (tau19 < (BOUND));                            \
  }

  float fx = fminf(qx, 1.f - qx), fy = fminf(qy, 1.f - qy),
        fz = fminf(qz, 1.f - qz);
  int nearf = (fx < 0.13f) + (fy < 0.13f) + (fz < 0.13f);

  if (nearf < 2) PASS(2, 5, 25, 0.0155f, 512, 0, INS8)
  if (!pass_ok)  PASS(3, 7, 49, 0.0351f, CAP, CAP, INS16)
#undef PASS

  if (!pass_ok) {
    // exact rescan of all 8192 with tau filter, from scratch (depth 20).
    // tau19 here is from the R3 pass: >= true d20 even when CAP-truncated
    // (lane minima / bitonic heads are unaffected by list depth).
#pragma unroll
    for (int j = 0; j < KNB; j++) key[j] = SENT;
    for (int g = 0; g < 32; g++) {
      int i0 = g * 256 + lane * 4;
#pragma unroll
      for (int c = 0; c < 4; c++) {
        float4 pk = bp[i0 + c];
        float dxv = qx - pk.x, dyv = qy - pk.y, dzv = qz - pk.z;
        float d2 = __fadd_rn(__fadd_rn(__fmul_rn(dxv, dxv),
                                       __fmul_rn(dyv, dyv)),
                             __fmul_rn(dzv, dzv));
        if (d2 <= tau19) {
          unsigned long long kk =
              ((unsigned long long)__float_as_uint(d2) << 32) |
              ((unsigned)__float_as_uint(pk.w) << 13) | (unsigned)(i0 + c);
          INS(kk)
        }
      }
    }
  }
#undef INS
#undef INS8
#undef INS16

  int bqoff = bq * NPTS;
  for (int step = 0; step < KNB; step++) {
    unsigned long long p = key[0];
    unsigned long long m = p;
#pragma unroll
    for (int off = 32; off >= 1; off >>= 1) {
      unsigned long long o = __shfl_xor(m, off);
      m = (o < m) ? o : m;
    }
    if (lane == 0) idxbuf[q * KNB + step] = bqoff + (int)(m & 0x1FFFULL);
    if (p == m) {
#pragma unroll
      for (int j = 0; j < KNB - 1; j++) key[j] = key[j + 1];
      key[KNB - 1] = SENT;
    }
  }
}

// ---------------------------------------------------------------------------
// K3: fused per-layer weight fold (R10-proven).
//  WA (64KB): A-frags of the STACKED operator [W2 | Wk'] (256 x K=128).
//  c0 (f32): pb2@aw1_bot.  WFB (40KB): B-frags for pre2: qh|v.
// ---------------------------------------------------------------------------
__global__ __launch_bounds__(256) void k_wf(const float* __restrict__ pw2,
                                            const float* __restrict__ pb2,
                                            const float* __restrict__ aw1,
                                            const float* __restrict__ qkvw,
                                            _Float16* __restrict__ WA,
                                            float* __restrict__ c0,
                                            _Float16* __restrict__ WFB) {
  int b = blockIdx.x;
  if (b < 65) {
    int h = b, c = threadIdx.x;
    float a = 0.f;
    if (h < 64) {
#pragma unroll 8
      for (int j = 0; j < 64; j++)
        a += pw2[h * 64 + j] * aw1[(size_t)(64 + j) * 256 + c];
      int mt = c >> 4, lo = c & 15;
      int ks = h >> 4, hi = (h >> 2) & 3, el = h & 3;
      WA[(size_t)(((mt * 8 + ks) * 64) + hi * 16 + lo) * 4 + el] = (_Float16)a;
    } else {
#pragma unroll 8
      for (int j = 0; j < 64; j++)
        a += pb2[j] * aw1[(size_t)(64 + j) * 256 + c];
      c0[c] = a;
    }
  } else {
    int id = (b - 65) * 256 + threadIdx.x;   // 144 blocks x 256 = 36864
    int h = id & 63, c = id >> 6;
    int ks = h >> 4, hi = (h >> 2) & 3, e = h & 3;
    float a = 0.f;
    if (c < 256) {
      // Wk' = Wk@aw1_top -> A-frag upper-K half (ks 4..7)
#pragma unroll 8
      for (int j = 0; j < 64; j++)
        a += qkvw[h * 192 + 64 + j] * aw1[(size_t)j * 256 + c];
      int mt = c >> 4, lo = c & 15;
      WA[(size_t)(((mt * 8 + 4 + ks) * 64) + hi * 16 + lo) * 4 + e] = (_Float16)a;
    } else if (c < 512) {
      int cc = c - 256;
#pragma unroll 8
      for (int j = 0; j < 64; j++)
        a += qkvw[h * 192 + j] * aw1[(size_t)j * 256 + cc];
      int nt = cc >> 4, lo = cc & 15;     // qh tiles 0..15
      WFB[(size_t)(((nt * 4 + ks) * 64) + hi * 16 + lo) * 4 + e] = (_Float16)a;
    } else {
      int cc = c - 512;
      a = qkvw[h * 192 + 128 + cc];
      int nt = 16 + (cc >> 4), lo = cc & 15;  // v tiles 16..19
      WFB[(size_t)(((nt * 4 + ks) * 64) + hi * 16 + lo) * 4 + e] = (_Float16)a;
    }
  }
}

// ---------------------------------------------------------------------------
// K3b: k_pre2 — MFMA GEMM producing qh|v only (R10-proven).
// ---------------------------------------------------------------------------
__global__ __launch_bounds__(256) void k_pre2(const float* __restrict__ x,
                                              const f16x4* __restrict__ WFB,
                                              const float* __restrict__ c0,
                                              const float* __restrict__ ab1,
                                              float* __restrict__ v,
                                              float* __restrict__ qh) {
  int tid = threadIdx.x;
  int wv = tid >> 6, lane = tid & 63;
  int mt = blockIdx.x * 4 + wv;
  int m0 = mt * 16;
  int lo = lane & 15, hi = lane >> 4;

  f16x4 af[4];
#pragma unroll
  for (int ks = 0; ks < 4; ks++) {
    float4 xv = *(const float4*)&x[(size_t)(m0 + lo) * 64 + ks * 16 + hi * 4];
    f16x4 a;
    a[0] = (_Float16)xv.x; a[1] = (_Float16)xv.y;
    a[2] = (_Float16)xv.z; a[3] = (_Float16)xv.w;
    af[ks] = a;
  }

#pragma unroll 4
  for (int nt = 0; nt < 20; nt++) {
    f32x4 acc = {0.f, 0.f, 0.f, 0.f};
#pragma unroll
    for (int ks = 0; ks < 4; ks++)
      acc = __builtin_amdgcn_mfma_f32_16x16x16f16(af[ks],
                                                  WFB[(nt * 4 + ks) * 64 + lane],
                                                  acc, 0, 0, 0);
    if (nt < 16) {
      int col = nt * 16 + lo;
      float bv = c0[col] + ab1[col];
#pragma unroll
      for (int r = 0; r < 4; r++)
        qh[(size_t)(m0 + hi * 4 + r) * 256 + col] = acc[r] + bv;
    } else {
      int col = (nt - 16) * 16 + lo;
#pragma unroll
      for (int r = 0; r < 4; r++)
        v[(size_t)(m0 + hi * 4 + r) * 64 + col] = acc[r];
    }
  }
}

// ---------------------------------------------------------------------------
// K4: attention — R11-proven (stacked K=128 MFMA, wave-parallel softmax).
//  Unchanged this round for attribution.
// ---------------------------------------------------------------------------
__global__ __launch_bounds__(256, 4) void k_attn(
    const float4* __restrict__ spk4, const float* __restrict__ v,
    const int* __restrict__ idxbuf, const float* __restrict__ xin,
    const float* __restrict__ qh,
    const float* __restrict__ pw1, const float* __restrict__ pb1,
    const float* __restrict__ pw2, const float* __restrict__ pb2,
    const _Float16* __restrict__ WA,
    const float* __restrict__ aw2, const float* __restrict__ ab2,
    float* __restrict__ xout) {
  __shared__ __align__(16) _Float16 s_t1x[4][2560];  // 20 KB: 20 rows x K=128
  __shared__ float s_sim[4][2][KNB];
  __shared__ int   s_nb[4][2][24];

  int tid = threadIdx.x;
  int wv = tid >> 6, lane = tid & 63;
  int q0 = blockIdx.x * 8 + wv * 2;          // this wave: queries q0, q0+1
  int lo = lane & 15, hi = lane >> 4;

  if (lane < KNB) {
    s_nb[wv][0][lane] = idxbuf[q0 * KNB + lane];
    s_nb[wv][1][lane] = idxbuf[(q0 + 1) * KNB + lane];
  }
  float4 qpa = spk4[q0];
  float4 qpb = spk4[q0 + 1];
  asm volatile("s_waitcnt lgkmcnt(0)" ::: "memory");  // s_nb visible to wave

  float w1x = pw1[lane], w1y = pw1[64 + lane], w1z = pw1[128 + lane];
  float b1h = pb1[lane];

  // A: per query: stage [t1(k=0..63); -x_g(k=64..127)] f16 swizzled -> frags.
  f16x4 bfab[2][8];
  f16x4 bf1[8];
#pragma unroll
  for (int ks = 0; ks < 8; ks++) {
    f16x4 z = {(_Float16)0.f, (_Float16)0.f, (_Float16)0.f, (_Float16)0.f};
    bf1[ks] = z;
  }
#pragma unroll
  for (int qq = 0; qq < 2; qq++) {
    float px = qq ? qpb.x : qpa.x;
    float py = qq ? qpb.y : qpa.y;
    float pz = qq ? qpb.z : qpa.z;
#pragma unroll
    for (int n = 0; n < KNB; n++) {
      int g = s_nb[wv][qq][n];
      float4 np = spk4[g];
      float t1n = fmaxf(b1h + (px - np.x) * w1x + (py - np.y) * w1y +
                            (pz - np.z) * w1z, 0.f);
      int sw = (n & 7) << 3;
      s_t1x[wv][n * 128 + (lane ^ sw)] = (_Float16)t1n;
      float xg = xin[(size_t)g * 64 + lane];
      s_t1x[wv][n * 128 + ((64 + lane) ^ sw)] = (_Float16)(-xg);
    }
    asm volatile("s_waitcnt lgkmcnt(0)" ::: "memory");  // writes visible
    // frags: lane(lo,hi) -> B[k=ks*16+4*hi..+3][col]; col=lo for main tile.
#pragma unroll
    for (int ks = 0; ks < 8; ks++) {
      int k0 = ks * 16 + hi * 4;
      bfab[qq][ks] =
          *(const f16x4*)&s_t1x[wv][lo * 128 + (k0 ^ ((lo & 7) << 3))];
      if (qq == 0) {
        if (lo < 4) {
          int n = 16 + lo;
          bf1[ks] = *(const f16x4*)&s_t1x[wv][n * 128 + (k0 ^ ((n & 7) << 3))];
        }
      } else {
        if (lo >= 4 && lo < 8) {
          int n = 12 + lo;        // 16 + (lo-4)
          bf1[ks] = *(const f16x4*)&s_t1x[wv][n * 128 + (k0 ^ ((n & 7) << 3))];
        }
      }
    }
    asm volatile("s_waitcnt lgkmcnt(0)" ::: "memory");  // reads done (WAR)
  }

  const f16x4* WA4 = (const f16x4*)WA;
  const float* qhra = &qh[(size_t)q0 * 256];
  const float* qhrb = &qh[(size_t)(q0 + 1) * 256];
  float sim0a = 0.f, sim0b = 0.f, sim1 = 0.f;

#pragma unroll 2
  for (int mt = 0; mt < 16; mt++) {
    f32x4 a0a = {0.f, 0.f, 0.f, 0.f};
    f32x4 a0b = {0.f, 0.f, 0.f, 0.f};
    f32x4 a1  = {0.f, 0.f, 0.f, 0.f};
#pragma unroll
    for (int ks = 0; ks < 8; ks++) {
      f16x4 af = WA4[(mt * 8 + ks) * 64 + lane];
      a0a = __builtin_amdgcn_mfma_f32_16x16x16f16(af, bfab[0][ks], a0a, 0, 0, 0);
      a0b = __builtin_amdgcn_mfma_f32_16x16x16f16(af, bfab[1][ks], a0b, 0, 0, 0);
      a1  = __builtin_amdgcn_mfma_f32_16x16x16f16(af, bf1[ks],     a1,  0, 0, 0);
    }
    int cb = mt * 16 + hi * 4;
    float4 w24 = *(const float4*)&aw2[cb];
    float4 qa4 = *(const float4*)&qhra[cb];
    float4 qb4 = *(const float4*)&qhrb[cb];
    sim0a += fmaxf(a0a[0] + qa4.x, 0.f) * w24.x +
             fmaxf(a0a[1] + qa4.y, 0.f) * w24.y +
             fmaxf(a0a[2] + qa4.z, 0.f) * w24.z +
             fmaxf(a0a[3] + qa4.w, 0.f) * w24.w;
    sim0b += fmaxf(a0b[0] + qb4.x, 0.f) * w24.x +
             fmaxf(a0b[1] + qb4.y, 0.f) * w24.y +
             fmaxf(a0b[2] + qb4.z, 0.f) * w24.z +
             fmaxf(a0b[3] + qb4.w, 0.f) * w24.w;
    float4 q14;                       // register select: q0 rows on lo<4
    q14.x = (lo < 4) ? qa4.x : qb4.x; q14.y = (lo < 4) ? qa4.y : qb4.y;
    q14.z = (lo < 4) ? qa4.z : qb4.z; q14.w = (lo < 4) ? qa4.w : qb4.w;
    sim1  += fmaxf(a1[0] + q14.x, 0.f) * w24.x +
             fmaxf(a1[1] + q14.y, 0.f) * w24.y +
             fmaxf(a1[2] + q14.z, 0.f) * w24.z +
             fmaxf(a1[3] + q14.w, 0.f) * w24.w;
  }
  // reduce over hi (XOR 16/32 keeps lo fixed; garbage lanes isolated).
  sim0a += __shfl_xor(sim0a, 16); sim0a += __shfl_xor(sim0a, 32);
  sim0b += __shfl_xor(sim0b, 16); sim0b += __shfl_xor(sim0b, 32);
  sim1  += __shfl_xor(sim1, 16);  sim1  += __shfl_xor(sim1, 32);
  float ab2v = ab2[0];
  if (lane < 16) s_sim[wv][0][lane] = sim0a + ab2v;
  if (lane < 16) s_sim[wv][1][lane] = sim0b + ab2v;
  if (lane < 4)       s_sim[wv][0][16 + lane] = sim1 + ab2v;       // q0 ovf
  else if (lane < 8)  s_sim[wv][1][12 + lane] = sim1 + ab2v;       // q1 ovf
  asm volatile("s_waitcnt lgkmcnt(0)" ::: "memory");  // s_sim visible

  // C: per query: wave-parallel softmax (shfl trees, exp cached in LDS);
  // out = inv*(sum e_n*v[g]) + (inv*(sum e_n*t1_n))@pw2 + pb2.
#define RL(x, l) __uint_as_float(__builtin_amdgcn_readlane(__float_as_uint(x), (l)))
#pragma unroll
  for (int qq = 0; qq < 2; qq++) {
    float px = qq ? qpb.x : qpa.x;
    float py = qq ? qpb.y : qpa.y;
    float pz = qq ? qpb.z : qpa.z;
    // lane n<20 owns sim_n; max/sum via 6-step shfl trees.
    float sv_ = (lane < KNB) ? s_sim[wv][qq][lane] : -3.402823466e38f;
    float mxv = sv_;
#pragma unroll
    for (int off = 32; off >= 1; off >>= 1)
      mxv = fmaxf(mxv, __shfl_xor(mxv, off));
    float e_ = (lane < KNB) ? expf(sv_ - mxv) : 0.f;
    if (lane < KNB) s_sim[wv][qq][lane] = e_;   // cache exp once
    float sumv = e_;
#pragma unroll
    for (int off = 32; off >= 1; off >>= 1) sumv += __shfl_xor(sumv, off);
    float inv = 1.f / sumv;
    asm volatile("s_waitcnt lgkmcnt(0)" ::: "memory");  // e_ writes visible
    float o = 0.f;
    float sac = 0.f;
#pragma unroll
    for (int n = 0; n < KNB; n++) {
      float en = s_sim[wv][qq][n];              // broadcast LDS read
      int g = s_nb[wv][qq][n];
      o += en * v[(size_t)g * 64 + lane];
      float4 np = spk4[g];
      float t1n = fmaxf(b1h + (px - np.x) * w1x + (py - np.y) * w1y +
                            (pz - np.z) * w1z, 0.f);
      sac += en * t1n;
    }
    o *= inv;
    sac *= inv;
    float r = pb2[lane];
    float r1 = 0.f;
#pragma unroll 4
    for (int j = 0; j < 64; j += 2) {
      r  += RL(sac, j)     * pw2[j * 64 + lane];
      r1 += RL(sac, j + 1) * pw2[(j + 1) * 64 + lane];
    }
    xout[(size_t)(q0 + qq) * 64 + lane] = o + r + r1;
  }
#undef RL
}

// ---------------------------------------------------------------------------
// K5a/K5b: parallel max-pool + head (order-invariant; sorted act OK).
// ---------------------------------------------------------------------------
__global__ __launch_bounds__(256) void k_pool(const float* __restrict__ x,
                                              float* __restrict__ pmax) {
  __shared__ float red[4][64];
  int b = blockIdx.x >> 6, blk = blockIdx.x & 63;
  int tid = threadIdx.x;
  int c = tid & 63, pg = tid >> 6;
  int p0 = blk * 128;
  float mx = -3.402823466e38f;
  for (int p = pg; p < 128; p += 4)
    mx = fmaxf(mx, x[((size_t)b * NPTS + p0 + p) * 64 + c]);
  red[pg][c] = mx;
  __syncthreads();
  if (tid < 64)
    pmax[(size_t)blockIdx.x * 64 + c] =
        fmaxf(fmaxf(red[0][c], red[1][c]), fmaxf(red[2][c], red[3][c]));
}

__global__ __launch_bounds__(256) void k_final2(const float* __restrict__ pmax,
                                                const float* __restrict__ fc1w,
                                                const float* __restrict__ fc1b,
                                                const float* __restrict__ fc3w,
                                                const float* __restrict__ fc3b,
                                                float* __restrict__ out) {
  __shared__ float red[4][64];
  __shared__ float m[64];
  __shared__ float h1[32];
  int b = blockIdx.x;
  int tid = threadIdx.x;
  int c = tid & 63, pg = tid >> 6;
  float mx = -3.402823466e38f;
  for (int blk = pg; blk < 64; blk += 4)
    mx = fmaxf(mx, pmax[(size_t)(b * 64 + blk) * 64 + c]);
  red[pg][c] = mx;
  __syncthreads();
  if (tid < 64)
    m[c] = fmaxf(fmaxf(red[0][c], red[1][c]), fmaxf(red[2][c], red[3][c]));
  __syncthreads();
  if (tid < 32) {
    float a = fc1b[tid];
#pragma unroll 8
    for (int k = 0; k < 64; k++) a += m[k] * fc1w[k * 32 + tid];
    h1[tid] = fmaxf(a, 0.f);
  }
  __syncthreads();
  if (tid < 3) {
    float a = fc3b[tid];
#pragma unroll
    for (int k = 0; k < 32; k++) a += h1[k] * fc3w[k * 3 + tid];
    out[b * 3 + tid] = a;
  }
}

// ---------------------------------------------------------------------------
// Workspace (peak ~44.8 MB):
//   idx @ 0 (1.31MB) | spk @ 1408KB (256KB; LIVE through both layers)
//   WA @ 1664KB (64KB f16 stacked A-frags) | c0 @ 1728KB (1KB)
//   pmax @ 1732KB (32KB) | cellStart @ 1764KB (33KB) | cnt+cnt2 @ 1800KB
//   WFB @ 1864KB (40KB) | v @ 2MB (4.2MB)
//   xb1 @ 6.5MB (4.2MB; layer ping-pong buffer)
//   qh @ 23.5MB (16.8MB) | act @ 40.5MB (4.2MB)
// ---------------------------------------------------------------------------
extern "C" void kernel_launch(void* const* d_in, const int* in_sizes, int n_in,
                              void* d_out, int out_size, void* d_ws,
                              size_t ws_size, hipStream_t stream) {
  const float* pts    = (const float*)d_in[0];
  const float* conv_w = (const float*)d_in[1];
  const float* conv_b = (const float*)d_in[2];
  const float* fc1w = (const float*)d_in[21];
  const float* fc1b = (const float*)d_in[22];
  const float* fc3w = (const float*)d_in[23];
  const float* fc3b = (const float*)d_in[24];
  float* outp = (float*)d_out;

  char* ws = (char*)d_ws;
  int*      idx   = (int*)    (ws);
  float4*   spk   = (float4*) (ws + (size_t)1408 * 1024);
  _Float16* WA    = (_Float16*)(ws + (size_t)1664 * 1024);  // 64KB
  float*    c0    = (float*)  (ws + (size_t)1728 * 1024);
  float*    pmax  = (float*)  (ws + (size_t)1732 * 1024);
  int*      cellS = (int*)    (ws + (size_t)1764 * 1024);
  int*      cnt   = (int*)    (ws + (size_t)1800 * 1024);   // cnt + cnt2
  int*      cnt2  = cnt + BATCH * NCELL;
  _Float16* WFB   = (_Float16*)(ws + (size_t)1864 * 1024);  // 40KB
  float*    v     = (float*)  (ws + (size_t)2 * 1048576);
  float*    xb1   = (float*)  (ws + (size_t)6656 * 1024);   // 4.2MB ping-pong
  float*    qh    = (float*)  (ws + (size_t)24064 * 1024);
  float*    act   = (float*)  (ws + (size_t)41472 * 1024);

  k_zero<<<(2 * BATCH * NCELL + 255) / 256, 256, 0, stream>>>(cnt);
  k_hist<<<(TOTAL + 255) / 256, 256, 0, stream>>>(pts, cnt);
  k_scan<<<BATCH, 256, 0, stream>>>(cnt, cellS);
  k_scatter<<<(TOTAL + 255) / 256, 256, 0, stream>>>(pts, cnt2, cellS, spk);
  k_conv<<<(TOTAL * 64 + 255) / 256, 256, 0, stream>>>(spk, conv_w, conv_b, act);
  k_knn<<<TOTAL / 4, 256, 0, stream>>>(spk, cellS, idx);

  for (int layer = 0; layer < 2; layer++) {
    int base = 3 + layer * 9;
    const float* qkvw = (const float*)d_in[base + 0];
    const float* pw1  = (const float*)d_in[base + 1];
    const float* pb1  = (const float*)d_in[base + 2];
    const float* pw2  = (const float*)d_in[base + 3];
    const float* pb2  = (const float*)d_in[base + 4];
    const float* aw1  = (const float*)d_in[base + 5];
    const float* ab1  = (const float*)d_in[base + 6];
    const float* aw2  = (const float*)d_in[base + 7];
    const float* ab2  = (const float*)d_in[base + 8];
    const float* xi = (layer == 0) ? act : xb1;   // layer input
    float*       xo = (layer == 0) ? xb1 : act;   // layer output (ping-pong)
    k_wf<<<209, 256, 0, stream>>>(pw2, pb2, aw1, qkvw, WA, c0, WFB);
    k_pre2<<<TOTAL / 64, 256, 0, stream>>>(xi, (const f16x4*)WFB, c0, ab1,
                                           v, qh);
    k_attn<<<TOTAL / 8, 256, 0, stream>>>(
        spk, v, idx, xi, qh, pw1, pb1, pw2, pb2, WA, aw2, ab2, xo);
  }
  k_pool<<<BATCH * 64, 256, 0, stream>>>(act, pmax);
  k_final2<<<BATCH, 256, 0, stream>>>(pmax, fc1w, fc1b, fc3w, fc3b, outp);
}